// Round 7
// baseline (1095.144 us; speedup 1.0000x reference)
//
#include <hip/hip_runtime.h>

// Pipeline (R3 reference-faithful order and numerics):
//   A = relu([x|st]@W1+b1)            [N,128]  mm1
//   B = relu(A@W2+b2)                 [N,64]   mm2 (h0)
//   A = B@Wg0                         [N,128]  mm3
//   B = relu(agg(A) + bg0)            [N,128]  agg1 (h1)
//   A = B@Wg1                         [N,128]  mm4
//   B = relu(agg(A) + bg1)            [N,128]  agg2 (h2)
//   A = B@Wg2                         [N,64]   mm5
//   out = agg(A) + bg2                [N,64]   agg3
// agg(hW)[i] = sum_{j in CSR row i} hW[ssrc[j]]*(dis[ssrc[j]]*dis[i])
//            + hW[i]*dis[i]^2
//
// R6 lesson: agg FETCH = 416 MB = 8 XCDs x 51 MB — every XCD streams the
// whole gather array through its private L2; stuck at ~3.35 TB/s L2-miss BW.
// R7: feature-sliced XCD-pinned agg — block g owns 64B slice (g % SLICES) of
// a 64-node tile; blockIdx%8 -> XCD round-robin pins each slice to 1 XCD
// (F=128) or 2 (F=64) => per-XCD unique bytes 51 MB -> 6.4 MB. Summation
// order per feature is unchanged (bitwise-identical to R6).

// ---------------- graph preprocessing (CSR by dst, int atomics only) --------

__global__ void k_count(const int* __restrict__ dst, int* __restrict__ cnt, int e) {
    int i = blockIdx.x * 256 + threadIdx.x;
    if (i < e) atomicAdd(&cnt[dst[i]], 1);
}

__global__ void k_dis(const int* __restrict__ cnt, float* __restrict__ dis, int n) {
    int i = blockIdx.x * 256 + threadIdx.x;
    if (i < n) dis[i] = rsqrtf(1.0f + (float)cnt[i]);
}

__global__ void k_blocksum(const int* __restrict__ cnt, int* __restrict__ bsum, int n) {
    __shared__ int sm[256];
    int t = threadIdx.x;
    int base = blockIdx.x * 1024;
    int s = 0;
#pragma unroll
    for (int i = 0; i < 4; i++) {
        int idx = base + i * 256 + t;
        if (idx < n) s += cnt[idx];
    }
    sm[t] = s;
    __syncthreads();
    for (int off = 128; off > 0; off >>= 1) {
        if (t < off) sm[t] += sm[t + off];
        __syncthreads();
    }
    if (t == 0) bsum[blockIdx.x] = sm[0];
}

__global__ void k_scansums(const int* __restrict__ bsum, int* __restrict__ boff, int nb) {
    __shared__ int sm[256];
    int t = threadIdx.x;
    int v = (t < nb) ? bsum[t] : 0;
    sm[t] = v;
    __syncthreads();
    for (int off = 1; off < 256; off <<= 1) {
        int add = (t >= off) ? sm[t - off] : 0;
        __syncthreads();
        sm[t] += add;
        __syncthreads();
    }
    if (t < nb) boff[t] = sm[t] - v;  // exclusive
}

__global__ void k_scatterscan(const int* __restrict__ cnt, const int* __restrict__ boff,
                              int* __restrict__ offs, int n) {
    __shared__ int sm[256];
    int t = threadIdx.x;
    int base = blockIdx.x * 1024 + t * 4;
    int v[4];
    int s = 0;
#pragma unroll
    for (int i = 0; i < 4; i++) {
        int idx = base + i;
        v[i] = (idx < n) ? cnt[idx] : 0;
        s += v[i];
    }
    sm[t] = s;
    __syncthreads();
    for (int off = 1; off < 256; off <<= 1) {
        int add = (t >= off) ? sm[t - off] : 0;
        __syncthreads();
        sm[t] += add;
        __syncthreads();
    }
    int run = boff[blockIdx.x] + sm[t] - s;
#pragma unroll
    for (int i = 0; i < 4; i++) {
        int idx = base + i;
        if (idx < n) {
            offs[idx] = run;
            run += v[i];
            if (idx == n - 1) offs[n] = run;
        }
    }
}

__global__ void k_fill(const int* __restrict__ src, const int* __restrict__ dst,
                       const int* __restrict__ offs, int* __restrict__ cur,
                       int* __restrict__ ssrc, int e) {
    int i = blockIdx.x * 256 + threadIdx.x;
    if (i < e) {
        int d = dst[i];
        int p = offs[d] + atomicAdd(&cur[d], 1);
        ssrc[p] = src[i];
    }
}

// Sort each CSR bucket ascending -> bitwise-deterministic aggregation.
__global__ __launch_bounds__(256) void k_sort(const int* __restrict__ offs,
                                              int* __restrict__ ssrc, int n) {
    const int wv = threadIdx.x >> 6;
    const int lane = threadIdx.x & 63;
    const int node = blockIdx.x * 4 + wv;
    if (node >= n) return;
    const int jb = offs[node];
    const int je = offs[node + 1];
    const int len = je - jb;
    if (len <= 1) return;
    if (len <= 64) {
        int v = (lane < len) ? ssrc[jb + lane] : 0x7fffffff;
#pragma unroll
        for (int k = 2; k <= 64; k <<= 1) {
            for (int j = k >> 1; j > 0; j >>= 1) {
                int p = __shfl_xor(v, j);
                bool lower = (lane & j) == 0;
                bool asc = (lane & k) == 0;
                v = (lower == asc) ? min(v, p) : max(v, p);
            }
        }
        if (lane < len) ssrc[jb + lane] = v;
    } else if (lane == 0) {
        for (int a = jb + 1; a < je; a++) {
            int key = ssrc[a];
            int b = a - 1;
            while (b >= jb && ssrc[b] > key) { ssrc[b + 1] = ssrc[b]; b--; }
            ssrc[b + 1] = key;
        }
    }
}

// ---------------- dense matmul: out[n,FOUT] = [in1|in2] @ W -----------------
// Block = 64 nodes x FOUT. 256 threads = 4 f-slices x 64 lanes (lane = node).
// A-tile staged in LDS (coalesced float4); W addresses wave-uniform -> s_load.

template <int FIN1, int FIN2, int FOUT, bool BIAS, bool RELU>
__global__ __launch_bounds__(256) void k_mm(const float* __restrict__ in1,
                                            const float* __restrict__ in2,
                                            const float* __restrict__ W,
                                            const float* __restrict__ bias,
                                            float* __restrict__ out, int n) {
    constexpr int FINT = FIN1 + FIN2;
    constexpr int ROWF = FINT + 4;   // +4 floats pad
    constexpr int JPT = FOUT / 4;    // outputs per thread (32 or 16)
    constexpr int NC4 = JPT / 4;     // float4 accumulators (8 or 4)

    __shared__ float lds[64 * ROWF];

    const int t = threadIdx.x;
    const int base = blockIdx.x * 64;

    {
        constexpr int R4 = FIN1 / 4;
        const float4* g = (const float4*)in1;
        for (int i = t; i < 64 * R4; i += 256) {
            int r = i / R4, c = i % R4;
            float4 v = (base + r < n) ? g[(size_t)(base + r) * R4 + c]
                                      : make_float4(0.f, 0.f, 0.f, 0.f);
            *(float4*)&lds[r * ROWF + c * 4] = v;
        }
    }
    if constexpr (FIN2 > 0) {
        constexpr int R4 = FIN2 / 4;
        const float4* g = (const float4*)in2;
        for (int i = t; i < 64 * R4; i += 256) {
            int r = i / R4, c = i % R4;
            float4 v = (base + r < n) ? g[(size_t)(base + r) * R4 + c]
                                      : make_float4(0.f, 0.f, 0.f, 0.f);
            *(float4*)&lds[r * ROWF + FIN1 + c * 4] = v;
        }
    }
    __syncthreads();

    const int lane = t & 63;
    const int f0 = __builtin_amdgcn_readfirstlane((t >> 6) * JPT);

    float4 c0, c1, c2, c3, c4, c5, c6, c7;
    if (BIAS) {
        const float4* b4 = (const float4*)(bias + f0);
        c0 = b4[0]; c1 = b4[1]; c2 = b4[2]; c3 = b4[3];
        if (NC4 == 8) { c4 = b4[4]; c5 = b4[5]; c6 = b4[6]; c7 = b4[7]; }
        else { c4 = c5 = c6 = c7 = make_float4(0.f, 0.f, 0.f, 0.f); }
    } else {
        c0 = c1 = c2 = c3 = c4 = c5 = c6 = c7 = make_float4(0.f, 0.f, 0.f, 0.f);
    }

#define FMA_BLK(av, wp)                                                                              \
    do {                                                                                             \
        const float4* _w4 = (const float4*)(wp);                                                     \
        { float4 _t = _w4[0]; c0.x = fmaf(av, _t.x, c0.x); c0.y = fmaf(av, _t.y, c0.y);              \
          c0.z = fmaf(av, _t.z, c0.z); c0.w = fmaf(av, _t.w, c0.w); }                                \
        { float4 _t = _w4[1]; c1.x = fmaf(av, _t.x, c1.x); c1.y = fmaf(av, _t.y, c1.y);              \
          c1.z = fmaf(av, _t.z, c1.z); c1.w = fmaf(av, _t.w, c1.w); }                                \
        { float4 _t = _w4[2]; c2.x = fmaf(av, _t.x, c2.x); c2.y = fmaf(av, _t.y, c2.y);              \
          c2.z = fmaf(av, _t.z, c2.z); c2.w = fmaf(av, _t.w, c2.w); }                                \
        { float4 _t = _w4[3]; c3.x = fmaf(av, _t.x, c3.x); c3.y = fmaf(av, _t.y, c3.y);              \
          c3.z = fmaf(av, _t.z, c3.z); c3.w = fmaf(av, _t.w, c3.w); }                                \
        if constexpr (NC4 == 8) {                                                                    \
            { float4 _t = _w4[4]; c4.x = fmaf(av, _t.x, c4.x); c4.y = fmaf(av, _t.y, c4.y);          \
              c4.z = fmaf(av, _t.z, c4.z); c4.w = fmaf(av, _t.w, c4.w); }                            \
            { float4 _t = _w4[5]; c5.x = fmaf(av, _t.x, c5.x); c5.y = fmaf(av, _t.y, c5.y);          \
              c5.z = fmaf(av, _t.z, c5.z); c5.w = fmaf(av, _t.w, c5.w); }                            \
            { float4 _t = _w4[6]; c6.x = fmaf(av, _t.x, c6.x); c6.y = fmaf(av, _t.y, c6.y);          \
              c6.z = fmaf(av, _t.z, c6.z); c6.w = fmaf(av, _t.w, c6.w); }                            \
            { float4 _t = _w4[7]; c7.x = fmaf(av, _t.x, c7.x); c7.y = fmaf(av, _t.y, c7.y);          \
              c7.z = fmaf(av, _t.z, c7.z); c7.w = fmaf(av, _t.w, c7.w); }                            \
        }                                                                                            \
    } while (0)

    const float* arow = &lds[lane * ROWF];
    for (int k = 0; k < FINT; k += 4) {
        float4 a = *(const float4*)(arow + k);
        const float* wr = W + (size_t)k * FOUT + f0;
        FMA_BLK(a.x, wr);
        FMA_BLK(a.y, wr + FOUT);
        FMA_BLK(a.z, wr + 2 * FOUT);
        FMA_BLK(a.w, wr + 3 * FOUT);
    }
#undef FMA_BLK

    const int node = base + lane;
    if (node < n) {
        if (RELU) {
#define RL(c) do { c.x = fmaxf(c.x, 0.f); c.y = fmaxf(c.y, 0.f); \
                   c.z = fmaxf(c.z, 0.f); c.w = fmaxf(c.w, 0.f); } while (0)
            RL(c0); RL(c1); RL(c2); RL(c3);
            if (NC4 == 8) { RL(c4); RL(c5); RL(c6); RL(c7); }
#undef RL
        }
        float4* orow = (float4*)(out + (size_t)node * FOUT + f0);
        orow[0] = c0; orow[1] = c1; orow[2] = c2; orow[3] = c3;
        if (NC4 == 8) { orow[4] = c4; orow[5] = c5; orow[6] = c6; orow[7] = c7; }
    }
}

// ---------------- GCN aggregation: feature-sliced, XCD-pinned ----------------
// Block g handles the 64B feature slice (g % SLICES) of 64 nodes
// (tile g / SLICES). blockIdx%8 -> XCD round-robin pins slice s to one XCD
// (F=128, SLICES=8) or two (F=64, SLICES=4): per-XCD unique gather bytes
// drop from N*F*4 to N*64. Wave = 16 node-groups x 4 lanes; each group walks
// its sorted bucket sequentially (per-feature fma order == R6, bitwise same);
// 4-deep index batching via intra-group __shfl for memory-level parallelism.

template <int F, bool RELU>
__global__ __launch_bounds__(256) void k_agg2(const float* __restrict__ hW,
                                              const float* __restrict__ bias,
                                              const float* __restrict__ dis,
                                              const int* __restrict__ offs,
                                              const int* __restrict__ ssrc,
                                              float* __restrict__ out, int n) {
    constexpr int SLICES = F / 16;        // 64 B slices
    const int slice = blockIdx.x % SLICES;
    const int tile = blockIdx.x / SLICES;
    const int t = threadIdx.x;
    const int wv = t >> 6;
    const int lane = t & 63;
    const int grp = lane >> 2;            // 16 groups per wave
    const int gl = lane & 3;              // lane-in-group: one float4 each
    const int node = tile * 64 + wv * 16 + grp;
    if (node >= n) return;

    const int jb = offs[node];
    const int je = offs[node + 1];
    const float di = dis[node];
    const float* rowbase = hW + slice * 16 + gl * 4;
    const int gbase = lane & ~3;

    float4 acc = make_float4(0.f, 0.f, 0.f, 0.f);
    int j = jb;
    for (; j + 4 <= je; j += 4) {
        int sv = ssrc[j + gl];            // 4 consecutive indices per group
        int s0 = __shfl(sv, gbase + 0);
        int s1 = __shfl(sv, gbase + 1);
        int s2 = __shfl(sv, gbase + 2);
        int s3 = __shfl(sv, gbase + 3);
        float w0 = dis[s0] * di;
        float w1 = dis[s1] * di;
        float w2 = dis[s2] * di;
        float w3 = dis[s3] * di;
        float4 h0 = *(const float4*)(rowbase + (size_t)s0 * F);
        float4 h1 = *(const float4*)(rowbase + (size_t)s1 * F);
        float4 h2 = *(const float4*)(rowbase + (size_t)s2 * F);
        float4 h3 = *(const float4*)(rowbase + (size_t)s3 * F);
        acc.x = fmaf(h0.x, w0, acc.x); acc.y = fmaf(h0.y, w0, acc.y);
        acc.z = fmaf(h0.z, w0, acc.z); acc.w = fmaf(h0.w, w0, acc.w);
        acc.x = fmaf(h1.x, w1, acc.x); acc.y = fmaf(h1.y, w1, acc.y);
        acc.z = fmaf(h1.z, w1, acc.z); acc.w = fmaf(h1.w, w1, acc.w);
        acc.x = fmaf(h2.x, w2, acc.x); acc.y = fmaf(h2.y, w2, acc.y);
        acc.z = fmaf(h2.z, w2, acc.z); acc.w = fmaf(h2.w, w2, acc.w);
        acc.x = fmaf(h3.x, w3, acc.x); acc.y = fmaf(h3.y, w3, acc.y);
        acc.z = fmaf(h3.z, w3, acc.z); acc.w = fmaf(h3.w, w3, acc.w);
    }
    for (; j < je; j++) {
        int s = ssrc[j];
        float w = dis[s] * di;
        float4 h = *(const float4*)(rowbase + (size_t)s * F);
        acc.x = fmaf(h.x, w, acc.x); acc.y = fmaf(h.y, w, acc.y);
        acc.z = fmaf(h.z, w, acc.z); acc.w = fmaf(h.w, w, acc.w);
    }

    const float sw = di * di;
    float4 self = *(const float4*)(rowbase + (size_t)node * F);
    float4 b4 = *(const float4*)(bias + slice * 16 + gl * 4);
    float4 v;
    v.x = acc.x + self.x * sw + b4.x;
    v.y = acc.y + self.y * sw + b4.y;
    v.z = acc.z + self.z * sw + b4.z;
    v.w = acc.w + self.w * sw + b4.w;
    if (RELU) {
        v.x = fmaxf(v.x, 0.f); v.y = fmaxf(v.y, 0.f);
        v.z = fmaxf(v.z, 0.f); v.w = fmaxf(v.w, 0.f);
    }
    *(float4*)(out + (size_t)node * F + slice * 16 + gl * 4) = v;
}

// ---------------- launch -----------------------------------------------------

extern "C" void kernel_launch(void* const* d_in, const int* in_sizes, int n_in,
                              void* d_out, int out_size, void* d_ws, size_t ws_size,
                              hipStream_t stream) {
    const float* x   = (const float*)d_in[0];
    const float* st  = (const float*)d_in[1];
    const int*   src = (const int*)d_in[2];
    const int*   dst = (const int*)d_in[3];
    const float* W1  = (const float*)d_in[4];
    const float* b1  = (const float*)d_in[5];
    const float* W2  = (const float*)d_in[6];
    const float* b2  = (const float*)d_in[7];
    const float* Wg0 = (const float*)d_in[8];
    const float* bg0 = (const float*)d_in[9];
    const float* Wg1 = (const float*)d_in[10];
    const float* bg1 = (const float*)d_in[11];
    const float* Wg2 = (const float*)d_in[12];
    const float* bg2 = (const float*)d_in[13];

    const int n = in_sizes[0] / 64;  // IN_DIM = 64
    const int e = in_sizes[2];

    char* wp = (char*)d_ws;
    auto carve = [&](size_t bytes) {
        void* p = (void*)wp;
        wp += (bytes + 255) & ~(size_t)255;
        return p;
    };
    int*   cnt  = (int*)carve((size_t)n * 4);
    int*   cur  = (int*)carve((size_t)n * 4);
    int*   offs = (int*)carve((size_t)(n + 1) * 4);
    float* dis  = (float*)carve((size_t)n * 4);
    int*   ssrc = (int*)carve((size_t)e * 4);
    float* bufA = (float*)carve((size_t)n * 128 * 4);
    float* bufB = (float*)carve((size_t)n * 128 * 4);
    const int nb1024 = (n + 1023) / 1024;
    int* bsum = (int*)carve((size_t)nb1024 * 4);
    int* boff = (int*)carve((size_t)nb1024 * 4);

    hipMemsetAsync(cnt, 0, (size_t)n * 4, stream);
    hipMemsetAsync(cur, 0, (size_t)n * 4, stream);

    const int gE = (e + 255) / 256;
    const int gN = (n + 255) / 256;
    const int gN64 = (n + 63) / 64;
    const int gAgg = (n + 3) / 4;

    // graph prep (ssrc sorted per bucket -> deterministic pipeline)
    k_count<<<gE, 256, 0, stream>>>(dst, cnt, e);
    k_dis<<<gN, 256, 0, stream>>>(cnt, dis, n);
    k_blocksum<<<nb1024, 256, 0, stream>>>(cnt, bsum, n);
    k_scansums<<<1, 256, 0, stream>>>(bsum, boff, nb1024);
    k_scatterscan<<<nb1024, 256, 0, stream>>>(cnt, boff, offs, n);
    k_fill<<<gE, 256, 0, stream>>>(src, dst, offs, cur, ssrc, e);
    k_sort<<<gAgg, 256, 0, stream>>>(offs, ssrc, n);

    // MLP
    k_mm<64, 32, 128, true, true><<<gN64, 256, 0, stream>>>(x, st, W1, b1, bufA, n);
    k_mm<128, 0, 64, true, true><<<gN64, 256, 0, stream>>>(bufA, nullptr, W2, b2, bufB, n);  // h0

    // conv0: mm -> agg@128 (bias+relu fused)
    k_mm<64, 0, 128, false, false><<<gN64, 256, 0, stream>>>(bufB, nullptr, Wg0, nullptr, bufA, n);
    k_agg2<128, true><<<gN64 * 8, 256, 0, stream>>>(bufA, bg0, dis, offs, ssrc, bufB, n);  // h1

    // conv1: mm -> agg@128 (bias+relu fused)
    k_mm<128, 0, 128, false, false><<<gN64, 256, 0, stream>>>(bufB, nullptr, Wg1, nullptr, bufA, n);
    k_agg2<128, true><<<gN64 * 8, 256, 0, stream>>>(bufA, bg1, dis, offs, ssrc, bufB, n);  // h2

    // conv2: mm -> agg@64 (bias, no relu) -> d_out
    k_mm<128, 0, 64, false, false><<<gN64, 256, 0, stream>>>(bufB, nullptr, Wg2, nullptr, bufA, n);
    k_agg2<64, false><<<gN64 * 4, 256, 0, stream>>>(bufA, bg2, dis, offs, ssrc, (float*)d_out, n);
}

// Round 8
// 766.446 us; speedup vs baseline: 1.4289x; 1.4289x over previous
//
#include <hip/hip_runtime.h>

// Pipeline (R3/R6 reference-faithful order and numerics; R8 = bf16 gather rows):
//   A = relu([x|st]@W1+b1)            [N,128]  mm1
//   B = relu(A@W2+b2)                 [N,64]   mm2 (h0)
//   P = bf16(B@Wg0)                   [N,128]  mm3 (P staged in d_out region)
//   A = relu(agg(P) + bg0)            [N,128]  agg1 (h1, fp32)
//   P = bf16(A@Wg1)                   [N,128]  mm4
//   B = relu(agg(P) + bg1)            [N,128]  agg2 (h2, fp32)
//   Q = bf16(B@Wg2)                   [N,64]   mm5 (Q aliases A region)
//   out = agg(Q) + bg2                [N,64]   agg3 -> d_out
// agg(hW)[i] = sum_{j in CSR row i} hW[ssrc[j]]*(dis[ssrc[j]]*dis[i])
//            + hW[i]*dis[i]^2        (fp32 accumulate, sorted-bucket order)
//
// R6 lesson: agg FETCH = 416 MB = 8 XCDs x 51.2 MB = "each XCD streams the
// whole fp32 gather array once" — the compulsory floor at ~3.4 TB/s.
// R7 lesson: feature-slicing broke line granularity + still thrashed 4MB L2
// (720 MB, 220us). R8: halve the array itself — bf16 rows, fp32 accumulate.
// Only the three pre-agg matrices are rounded; error budget ~+2e-3.

__device__ __forceinline__ unsigned short bf16rne(float f) {
    unsigned u = __float_as_uint(f);
    unsigned r = (u + 0x7fffu + ((u >> 16) & 1u)) >> 16;
    return (unsigned short)r;
}
__device__ __forceinline__ float bf16tof(unsigned short v) {
    return __uint_as_float((unsigned)v << 16);
}

// ---------------- graph preprocessing (CSR by dst, int atomics only) --------

__global__ void k_count(const int* __restrict__ dst, int* __restrict__ cnt, int e) {
    int i = blockIdx.x * 256 + threadIdx.x;
    if (i < e) atomicAdd(&cnt[dst[i]], 1);
}

__global__ void k_dis(const int* __restrict__ cnt, float* __restrict__ dis, int n) {
    int i = blockIdx.x * 256 + threadIdx.x;
    if (i < n) dis[i] = rsqrtf(1.0f + (float)cnt[i]);
}

__global__ void k_blocksum(const int* __restrict__ cnt, int* __restrict__ bsum, int n) {
    __shared__ int sm[256];
    int t = threadIdx.x;
    int base = blockIdx.x * 1024;
    int s = 0;
#pragma unroll
    for (int i = 0; i < 4; i++) {
        int idx = base + i * 256 + t;
        if (idx < n) s += cnt[idx];
    }
    sm[t] = s;
    __syncthreads();
    for (int off = 128; off > 0; off >>= 1) {
        if (t < off) sm[t] += sm[t + off];
        __syncthreads();
    }
    if (t == 0) bsum[blockIdx.x] = sm[0];
}

__global__ void k_scansums(const int* __restrict__ bsum, int* __restrict__ boff, int nb) {
    __shared__ int sm[256];
    int t = threadIdx.x;
    int v = (t < nb) ? bsum[t] : 0;
    sm[t] = v;
    __syncthreads();
    for (int off = 1; off < 256; off <<= 1) {
        int add = (t >= off) ? sm[t - off] : 0;
        __syncthreads();
        sm[t] += add;
        __syncthreads();
    }
    if (t < nb) boff[t] = sm[t] - v;  // exclusive
}

__global__ void k_scatterscan(const int* __restrict__ cnt, const int* __restrict__ boff,
                              int* __restrict__ offs, int n) {
    __shared__ int sm[256];
    int t = threadIdx.x;
    int base = blockIdx.x * 1024 + t * 4;
    int v[4];
    int s = 0;
#pragma unroll
    for (int i = 0; i < 4; i++) {
        int idx = base + i;
        v[i] = (idx < n) ? cnt[idx] : 0;
        s += v[i];
    }
    sm[t] = s;
    __syncthreads();
    for (int off = 1; off < 256; off <<= 1) {
        int add = (t >= off) ? sm[t - off] : 0;
        __syncthreads();
        sm[t] += add;
        __syncthreads();
    }
    int run = boff[blockIdx.x] + sm[t] - s;
#pragma unroll
    for (int i = 0; i < 4; i++) {
        int idx = base + i;
        if (idx < n) {
            offs[idx] = run;
            run += v[i];
            if (idx == n - 1) offs[n] = run;
        }
    }
}

__global__ void k_fill(const int* __restrict__ src, const int* __restrict__ dst,
                       const int* __restrict__ offs, int* __restrict__ cur,
                       int* __restrict__ ssrc, int e) {
    int i = blockIdx.x * 256 + threadIdx.x;
    if (i < e) {
        int d = dst[i];
        int p = offs[d] + atomicAdd(&cur[d], 1);
        ssrc[p] = src[i];
    }
}

// Sort each CSR bucket ascending -> bitwise-deterministic aggregation.
__global__ __launch_bounds__(256) void k_sort(const int* __restrict__ offs,
                                              int* __restrict__ ssrc, int n) {
    const int wv = threadIdx.x >> 6;
    const int lane = threadIdx.x & 63;
    const int node = blockIdx.x * 4 + wv;
    if (node >= n) return;
    const int jb = offs[node];
    const int je = offs[node + 1];
    const int len = je - jb;
    if (len <= 1) return;
    if (len <= 64) {
        int v = (lane < len) ? ssrc[jb + lane] : 0x7fffffff;
#pragma unroll
        for (int k = 2; k <= 64; k <<= 1) {
            for (int j = k >> 1; j > 0; j >>= 1) {
                int p = __shfl_xor(v, j);
                bool lower = (lane & j) == 0;
                bool asc = (lane & k) == 0;
                v = (lower == asc) ? min(v, p) : max(v, p);
            }
        }
        if (lane < len) ssrc[jb + lane] = v;
    } else if (lane == 0) {
        for (int a = jb + 1; a < je; a++) {
            int key = ssrc[a];
            int b = a - 1;
            while (b >= jb && ssrc[b] > key) { ssrc[b + 1] = ssrc[b]; b--; }
            ssrc[b + 1] = key;
        }
    }
}

// ---------------- dense matmul: out[n,FOUT] = [in1|in2] @ W -----------------
// Block = 64 nodes x FOUT. 256 threads = 4 f-slices x 64 lanes (lane = node).
// A-tile staged in LDS (coalesced float4); W addresses wave-uniform -> s_load.
// OBF16: epilogue rounds outputs to bf16 (RNE) and stores packed ushort4.

template <int FIN1, int FIN2, int FOUT, bool BIAS, bool RELU, bool OBF16>
__global__ __launch_bounds__(256) void k_mm(const float* __restrict__ in1,
                                            const float* __restrict__ in2,
                                            const float* __restrict__ W,
                                            const float* __restrict__ bias,
                                            void* __restrict__ outv, int n) {
    constexpr int FINT = FIN1 + FIN2;
    constexpr int ROWF = FINT + 4;   // +4 floats pad
    constexpr int JPT = FOUT / 4;    // outputs per thread (32 or 16)
    constexpr int NC4 = JPT / 4;     // float4 accumulators (8 or 4)

    __shared__ float lds[64 * ROWF];

    const int t = threadIdx.x;
    const int base = blockIdx.x * 64;

    {
        constexpr int R4 = FIN1 / 4;
        const float4* g = (const float4*)in1;
        for (int i = t; i < 64 * R4; i += 256) {
            int r = i / R4, c = i % R4;
            float4 v = (base + r < n) ? g[(size_t)(base + r) * R4 + c]
                                      : make_float4(0.f, 0.f, 0.f, 0.f);
            *(float4*)&lds[r * ROWF + c * 4] = v;
        }
    }
    if constexpr (FIN2 > 0) {
        constexpr int R4 = FIN2 / 4;
        const float4* g = (const float4*)in2;
        for (int i = t; i < 64 * R4; i += 256) {
            int r = i / R4, c = i % R4;
            float4 v = (base + r < n) ? g[(size_t)(base + r) * R4 + c]
                                      : make_float4(0.f, 0.f, 0.f, 0.f);
            *(float4*)&lds[r * ROWF + FIN1 + c * 4] = v;
        }
    }
    __syncthreads();

    const int lane = t & 63;
    const int f0 = __builtin_amdgcn_readfirstlane((t >> 6) * JPT);

    float4 c0, c1, c2, c3, c4, c5, c6, c7;
    if (BIAS) {
        const float4* b4 = (const float4*)(bias + f0);
        c0 = b4[0]; c1 = b4[1]; c2 = b4[2]; c3 = b4[3];
        if (NC4 == 8) { c4 = b4[4]; c5 = b4[5]; c6 = b4[6]; c7 = b4[7]; }
        else { c4 = c5 = c6 = c7 = make_float4(0.f, 0.f, 0.f, 0.f); }
    } else {
        c0 = c1 = c2 = c3 = c4 = c5 = c6 = c7 = make_float4(0.f, 0.f, 0.f, 0.f);
    }

#define FMA_BLK(av, wp)                                                                              \
    do {                                                                                             \
        const float4* _w4 = (const float4*)(wp);                                                     \
        { float4 _t = _w4[0]; c0.x = fmaf(av, _t.x, c0.x); c0.y = fmaf(av, _t.y, c0.y);              \
          c0.z = fmaf(av, _t.z, c0.z); c0.w = fmaf(av, _t.w, c0.w); }                                \
        { float4 _t = _w4[1]; c1.x = fmaf(av, _t.x, c1.x); c1.y = fmaf(av, _t.y, c1.y);              \
          c1.z = fmaf(av, _t.z, c1.z); c1.w = fmaf(av, _t.w, c1.w); }                                \
        { float4 _t = _w4[2]; c2.x = fmaf(av, _t.x, c2.x); c2.y = fmaf(av, _t.y, c2.y);              \
          c2.z = fmaf(av, _t.z, c2.z); c2.w = fmaf(av, _t.w, c2.w); }                                \
        { float4 _t = _w4[3]; c3.x = fmaf(av, _t.x, c3.x); c3.y = fmaf(av, _t.y, c3.y);              \
          c3.z = fmaf(av, _t.z, c3.z); c3.w = fmaf(av, _t.w, c3.w); }                                \
        if constexpr (NC4 == 8) {                                                                    \
            { float4 _t = _w4[4]; c4.x = fmaf(av, _t.x, c4.x); c4.y = fmaf(av, _t.y, c4.y);          \
              c4.z = fmaf(av, _t.z, c4.z); c4.w = fmaf(av, _t.w, c4.w); }                            \
            { float4 _t = _w4[5]; c5.x = fmaf(av, _t.x, c5.x); c5.y = fmaf(av, _t.y, c5.y);          \
              c5.z = fmaf(av, _t.z, c5.z); c5.w = fmaf(av, _t.w, c5.w); }                            \
            { float4 _t = _w4[6]; c6.x = fmaf(av, _t.x, c6.x); c6.y = fmaf(av, _t.y, c6.y);          \
              c6.z = fmaf(av, _t.z, c6.z); c6.w = fmaf(av, _t.w, c6.w); }                            \
            { float4 _t = _w4[7]; c7.x = fmaf(av, _t.x, c7.x); c7.y = fmaf(av, _t.y, c7.y);          \
              c7.z = fmaf(av, _t.z, c7.z); c7.w = fmaf(av, _t.w, c7.w); }                            \
        }                                                                                            \
    } while (0)

    const float* arow = &lds[lane * ROWF];
    for (int k = 0; k < FINT; k += 4) {
        float4 a = *(const float4*)(arow + k);
        const float* wr = W + (size_t)k * FOUT + f0;
        FMA_BLK(a.x, wr);
        FMA_BLK(a.y, wr + FOUT);
        FMA_BLK(a.z, wr + 2 * FOUT);
        FMA_BLK(a.w, wr + 3 * FOUT);
    }
#undef FMA_BLK

    const int node = base + lane;
    if (node < n) {
        if (RELU) {
#define RL(c) do { c.x = fmaxf(c.x, 0.f); c.y = fmaxf(c.y, 0.f); \
                   c.z = fmaxf(c.z, 0.f); c.w = fmaxf(c.w, 0.f); } while (0)
            RL(c0); RL(c1); RL(c2); RL(c3);
            if (NC4 == 8) { RL(c4); RL(c5); RL(c6); RL(c7); }
#undef RL
        }
        if constexpr (OBF16) {
            unsigned short* orow = (unsigned short*)outv + (size_t)node * FOUT + f0;
#define ST4(i, c)                                                                  \
            do {                                                                   \
                ushort4 r;                                                         \
                r.x = bf16rne(c.x); r.y = bf16rne(c.y);                            \
                r.z = bf16rne(c.z); r.w = bf16rne(c.w);                            \
                *(ushort4*)(orow + (i) * 4) = r;                                   \
            } while (0)
            ST4(0, c0); ST4(1, c1); ST4(2, c2); ST4(3, c3);
            if (NC4 == 8) { ST4(4, c4); ST4(5, c5); ST4(6, c6); ST4(7, c7); }
#undef ST4
        } else {
            float4* orow = (float4*)((float*)outv + (size_t)node * FOUT + f0);
            orow[0] = c0; orow[1] = c1; orow[2] = c2; orow[3] = c3;
            if (NC4 == 8) { orow[4] = c4; orow[5] = c5; orow[6] = c6; orow[7] = c7; }
        }
    }
}

// ---------------- GCN aggregation (bf16 rows, fp32 accumulate) --------------
// out[i] = sum_j hW[ssrc[j]] * (dis[ssrc[j]]*dis[i])   (sorted CSR order)
//        + hW[i]*dis[i]^2 + bias   (optional relu)
// Wave per node, lane owns FPL consecutive features. Loads batched 8 edges
// deep (independent gathers in flight); fma chain order fixed & sequential.

template <int F, bool RELU>
__global__ __launch_bounds__(256) void k_agg(const unsigned short* __restrict__ hW,
                                             const float* __restrict__ bias,
                                             const float* __restrict__ dis,
                                             const int* __restrict__ offs,
                                             const int* __restrict__ ssrc,
                                             float* __restrict__ out, int n) {
    const int wv = threadIdx.x >> 6;
    const int lane = threadIdx.x & 63;
    const int node = blockIdx.x * 4 + wv;
    if (node >= n) return;

    constexpr int FPL = F / 64;  // bf16 per lane (1 or 2)
    const int jb = offs[node];
    const int je = offs[node + 1];
    const float di = dis[node];
    const unsigned short* lbase = hW + lane * FPL;

    float accx = 0.f, accy = 0.f;
    int j = jb;
    for (; j + 8 <= je; j += 8) {
        int s[8];
#pragma unroll
        for (int k = 0; k < 8; k++) s[k] = ssrc[j + k];
        float w[8];
#pragma unroll
        for (int k = 0; k < 8; k++) w[k] = dis[s[k]] * di;
        float hx[8], hy[8];
#pragma unroll
        for (int k = 0; k < 8; k++) {
            if constexpr (FPL == 2) {
                unsigned v = *(const unsigned*)(lbase + (size_t)s[k] * F);
                hx[k] = __uint_as_float(v << 16);
                hy[k] = __uint_as_float(v & 0xffff0000u);
            } else {
                hx[k] = bf16tof(lbase[(size_t)s[k] * F]);
            }
        }
#pragma unroll
        for (int k = 0; k < 8; k++) {
            accx = fmaf(hx[k], w[k], accx);
            if constexpr (FPL == 2) accy = fmaf(hy[k], w[k], accy);
        }
    }
    for (; j < je; j++) {
        int s = ssrc[j];
        float w = dis[s] * di;
        if constexpr (FPL == 2) {
            unsigned v = *(const unsigned*)(lbase + (size_t)s * F);
            accx = fmaf(__uint_as_float(v << 16), w, accx);
            accy = fmaf(__uint_as_float(v & 0xffff0000u), w, accy);
        } else {
            accx = fmaf(bf16tof(lbase[(size_t)s * F]), w, accx);
        }
    }

    const float sw = di * di;
    if constexpr (FPL == 2) {
        unsigned v = *(const unsigned*)(hW + (size_t)node * F + lane * 2);
        float hsx = __uint_as_float(v << 16);
        float hsy = __uint_as_float(v & 0xffff0000u);
        float2 bb = *(const float2*)(bias + lane * 2);
        float vx = accx + hsx * sw + bb.x;
        float vy = accy + hsy * sw + bb.y;
        if (RELU) { vx = fmaxf(vx, 0.f); vy = fmaxf(vy, 0.f); }
        *(float2*)(out + (size_t)node * F + lane * 2) = make_float2(vx, vy);
    } else {
        float hs = bf16tof(hW[(size_t)node * F + lane]);
        float v = accx + hs * sw + bias[lane];
        if (RELU) v = fmaxf(v, 0.f);
        out[(size_t)node * F + lane] = v;
    }
}

// ---------------- launch -----------------------------------------------------

extern "C" void kernel_launch(void* const* d_in, const int* in_sizes, int n_in,
                              void* d_out, int out_size, void* d_ws, size_t ws_size,
                              hipStream_t stream) {
    const float* x   = (const float*)d_in[0];
    const float* st  = (const float*)d_in[1];
    const int*   src = (const int*)d_in[2];
    const int*   dst = (const int*)d_in[3];
    const float* W1  = (const float*)d_in[4];
    const float* b1  = (const float*)d_in[5];
    const float* W2  = (const float*)d_in[6];
    const float* b2  = (const float*)d_in[7];
    const float* Wg0 = (const float*)d_in[8];
    const float* bg0 = (const float*)d_in[9];
    const float* Wg1 = (const float*)d_in[10];
    const float* bg1 = (const float*)d_in[11];
    const float* Wg2 = (const float*)d_in[12];
    const float* bg2 = (const float*)d_in[13];

    const int n = in_sizes[0] / 64;  // IN_DIM = 64
    const int e = in_sizes[2];

    char* wp = (char*)d_ws;
    auto carve = [&](size_t bytes) {
        void* p = (void*)wp;
        wp += (bytes + 255) & ~(size_t)255;
        return p;
    };
    int*   cnt  = (int*)carve((size_t)n * 4);
    int*   cur  = (int*)carve((size_t)n * 4);
    int*   offs = (int*)carve((size_t)(n + 1) * 4);
    float* dis  = (float*)carve((size_t)n * 4);
    int*   ssrc = (int*)carve((size_t)e * 4);
    float* bufA = (float*)carve((size_t)n * 128 * 4);
    float* bufB = (float*)carve((size_t)n * 128 * 4);
    const int nb1024 = (n + 1023) / 1024;
    int* bsum = (int*)carve((size_t)nb1024 * 4);
    int* boff = (int*)carve((size_t)nb1024 * 4);

    // bf16 staging: P (n x 128 bf16 = n*256 B) lives in d_out (n*64 fp32 =
    // n*256 B, dead until agg3); Q (n x 64 bf16) aliases bufA (dead by mm5).
    unsigned short* P = (unsigned short*)d_out;
    unsigned short* Q = (unsigned short*)bufA;

    hipMemsetAsync(cnt, 0, (size_t)n * 4, stream);
    hipMemsetAsync(cur, 0, (size_t)n * 4, stream);

    const int gE = (e + 255) / 256;
    const int gN = (n + 255) / 256;
    const int gN64 = (n + 63) / 64;
    const int gAgg = (n + 3) / 4;

    // graph prep (ssrc sorted per bucket -> deterministic pipeline)
    k_count<<<gE, 256, 0, stream>>>(dst, cnt, e);
    k_dis<<<gN, 256, 0, stream>>>(cnt, dis, n);
    k_blocksum<<<nb1024, 256, 0, stream>>>(cnt, bsum, n);
    k_scansums<<<1, 256, 0, stream>>>(bsum, boff, nb1024);
    k_scatterscan<<<nb1024, 256, 0, stream>>>(cnt, boff, offs, n);
    k_fill<<<gE, 256, 0, stream>>>(src, dst, offs, cur, ssrc, e);
    k_sort<<<gAgg, 256, 0, stream>>>(offs, ssrc, n);

    // MLP
    k_mm<64, 32, 128, true, true, false><<<gN64, 256, 0, stream>>>(x, st, W1, b1, bufA, n);
    k_mm<128, 0, 64, true, true, false><<<gN64, 256, 0, stream>>>(bufA, nullptr, W2, b2, bufB, n);  // h0

    // conv0: mm (bf16 out) -> agg@128 (bias+relu fused)
    k_mm<64, 0, 128, false, false, true><<<gN64, 256, 0, stream>>>(bufB, nullptr, Wg0, nullptr, P, n);
    k_agg<128, true><<<gAgg, 256, 0, stream>>>(P, bg0, dis, offs, ssrc, bufA, n);  // h1

    // conv1: mm (bf16 out) -> agg@128 (bias+relu fused)
    k_mm<128, 0, 128, false, false, true><<<gN64, 256, 0, stream>>>(bufA, nullptr, Wg1, nullptr, P, n);
    k_agg<128, true><<<gAgg, 256, 0, stream>>>(P, bg1, dis, offs, ssrc, bufB, n);  // h2

    // conv2: mm (bf16 out) -> agg@64 (bias, no relu) -> d_out
    k_mm<128, 0, 64, false, false, true><<<gN64, 256, 0, stream>>>(bufB, nullptr, Wg2, nullptr, Q, n);
    k_agg<64, false><<<gAgg, 256, 0, stream>>>(Q, bg2, dis, offs, ssrc, (float*)d_out, n);
}

// Round 9
// 651.599 us; speedup vs baseline: 1.6807x; 1.1763x over previous
//
#include <hip/hip_runtime.h>

// Pipeline (R3/R6 order; R8 bf16 gather rows; R9 bucketed CSR build):
//   A = relu([x|st]@W1+b1)            [N,128]  mm1
//   B = relu(A@W2+b2)                 [N,64]   mm2 (h0)
//   P = bf16(B@Wg0)                   [N,128]  mm3 (P staged in d_out region)
//   A = relu(agg(P) + bg0)            [N,128]  agg1 (h1, fp32)
//   P = bf16(A@Wg1)                   [N,128]  mm4
//   B = relu(agg(P) + bg1)            [N,128]  agg2 (h2, fp32)
//   Q = bf16(B@Wg2)                   [N,64]   mm5 (Q aliases bufA)
//   out = agg(Q) + bg2                [N,64]   agg3 -> d_out
//
// R8 lesson: k_fill's random 4B CSR scatter = 1.6M dirty 64B sectors
// (WRITE_SIZE 107MB, 100us at 1.2TB/s). R9: two-level bucketed build —
// coarse 256-node buckets (dst>>8), block-local LDS binning with chunk
// reservation (dense 8B-pair bursts), then per-bucket placement inside a
// 16KB L2-hot region. k_sort still canonicalizes order -> numerics
// bitwise-identical to R8.

__device__ __forceinline__ unsigned short bf16rne(float f) {
    unsigned u = __float_as_uint(f);
    unsigned r = (u + 0x7fffu + ((u >> 16) & 1u)) >> 16;
    return (unsigned short)r;
}
__device__ __forceinline__ float bf16tof(unsigned short v) {
    return __uint_as_float((unsigned)v << 16);
}

// ---------------- graph preprocessing: bucketed CSR (dst>>8 buckets) --------
// NB = ceil(n/256) buckets (<=512 for n<=131072).

__global__ __launch_bounds__(256) void k_hist(const int* __restrict__ dst, int e, int nb,
                                              int* __restrict__ gh) {
    __shared__ int h[512];
    const int t = threadIdx.x;
    h[t] = 0; h[t + 256] = 0;
    __syncthreads();
    const int base = blockIdx.x * 4096;
    const int end = min(base + 4096, e);
    for (int i = base + t; i < end; i += 256) atomicAdd(&h[dst[i] >> 8], 1);
    __syncthreads();
    for (int b = t; b < nb; b += 256)
        if (h[b]) atomicAdd(&gh[b], h[b]);
}

// 1 block, 512 threads: exclusive scan of gh[0..nb) -> bbase, init gcur=bbase,
// bbase[nb]=e, offs[n]=e.
__global__ __launch_bounds__(512) void k_scan(const int* __restrict__ gh, int nb, int e, int n,
                                              int* __restrict__ bbase, int* __restrict__ gcur,
                                              int* __restrict__ offs) {
    __shared__ int sm[512];
    const int t = threadIdx.x;
    int v = (t < nb) ? gh[t] : 0;
    sm[t] = v;
    __syncthreads();
    for (int off = 1; off < 512; off <<= 1) {
        int add = (t >= off) ? sm[t - off] : 0;
        __syncthreads();
        sm[t] += add;
        __syncthreads();
    }
    if (t < nb) {
        int excl = sm[t] - v;
        bbase[t] = excl;
        gcur[t] = excl;
    }
    if (t == 0) { bbase[nb] = e; offs[n] = e; }
}

// Block bins 4096 edges by bucket in LDS, reserves one contiguous chunk per
// (block,bucket) via a single global atomicAdd, writes (src,dst) pairs densely.
__global__ __launch_bounds__(256) void k_scatter1(const int* __restrict__ src,
                                                  const int* __restrict__ dst, int e, int nb,
                                                  int* __restrict__ gcur,
                                                  int2* __restrict__ ep) {
    __shared__ int h[512];
    __shared__ int cbase[512];
    const int t = threadIdx.x;
    h[t] = 0; h[t + 256] = 0;
    __syncthreads();
    const int base = blockIdx.x * 4096;
    const int end = min(base + 4096, e);
    for (int i = base + t; i < end; i += 256) atomicAdd(&h[dst[i] >> 8], 1);
    __syncthreads();
    for (int b = t; b < nb; b += 256) {
        int c = h[b];
        cbase[b] = c ? atomicAdd(&gcur[b], c) : 0;
        h[b] = 0;
    }
    __syncthreads();
    for (int i = base + t; i < end; i += 256) {
        int d = dst[i];
        int bn = d >> 8;
        int r = atomicAdd(&h[bn], 1);
        ep[cbase[bn] + r] = make_int2(src[i], d);
    }
}

// One block per bucket: per-node count + scan -> offs (coalesced); place ssrc
// within the bucket's contiguous region (L2-hot, dense writebacks).
__global__ __launch_bounds__(256) void k_build(const int2* __restrict__ ep,
                                               const int* __restrict__ bbase, int n,
                                               int* __restrict__ offs,
                                               int* __restrict__ ssrc) {
    __shared__ int cnt[256];
    __shared__ int sm[256];
    __shared__ int cur[256];
    const int t = threadIdx.x;
    const int b = blockIdx.x;
    const int lo = bbase[b];
    const int hi = bbase[b + 1];
    cnt[t] = 0;
    __syncthreads();
    for (int i = lo + t; i < hi; i += 256) atomicAdd(&cnt[ep[i].y & 255], 1);
    __syncthreads();
    int v = cnt[t];
    sm[t] = v;
    __syncthreads();
    for (int off = 1; off < 256; off <<= 1) {
        int add = (t >= off) ? sm[t - off] : 0;
        __syncthreads();
        sm[t] += add;
        __syncthreads();
    }
    const int excl = sm[t] - v;
    const int node = (b << 8) + t;
    if (node < n) offs[node] = lo + excl;
    cur[t] = lo + excl;
    __syncthreads();
    for (int i = lo + t; i < hi; i += 256) {
        int2 p = ep[i];
        int pos = atomicAdd(&cur[p.y & 255], 1);
        ssrc[pos] = p.x;
    }
}

__global__ void k_dis(const int* __restrict__ offs, float* __restrict__ dis, int n) {
    int i = blockIdx.x * 256 + threadIdx.x;
    if (i < n) dis[i] = rsqrtf(1.0f + (float)(offs[i + 1] - offs[i]));
}

// Sort each CSR bucket ascending -> bitwise-deterministic aggregation.
__global__ __launch_bounds__(256) void k_sort(const int* __restrict__ offs,
                                              int* __restrict__ ssrc, int n) {
    const int wv = threadIdx.x >> 6;
    const int lane = threadIdx.x & 63;
    const int node = blockIdx.x * 4 + wv;
    if (node >= n) return;
    const int jb = offs[node];
    const int je = offs[node + 1];
    const int len = je - jb;
    if (len <= 1) return;
    if (len <= 64) {
        int v = (lane < len) ? ssrc[jb + lane] : 0x7fffffff;
#pragma unroll
        for (int k = 2; k <= 64; k <<= 1) {
            for (int j = k >> 1; j > 0; j >>= 1) {
                int p = __shfl_xor(v, j);
                bool lower = (lane & j) == 0;
                bool asc = (lane & k) == 0;
                v = (lower == asc) ? min(v, p) : max(v, p);
            }
        }
        if (lane < len) ssrc[jb + lane] = v;
    } else if (lane == 0) {
        for (int a = jb + 1; a < je; a++) {
            int key = ssrc[a];
            int b = a - 1;
            while (b >= jb && ssrc[b] > key) { ssrc[b + 1] = ssrc[b]; b--; }
            ssrc[b + 1] = key;
        }
    }
}

// ---------------- dense matmul: out[n,FOUT] = [in1|in2] @ W -----------------
// Block = 64 nodes x FOUT. 256 threads = 4 f-slices x 64 lanes (lane = node).
// A-tile staged in LDS (coalesced float4); W addresses wave-uniform -> s_load.
// OBF16: epilogue rounds outputs to bf16 (RNE) and stores packed ushort4.

template <int FIN1, int FIN2, int FOUT, bool BIAS, bool RELU, bool OBF16>
__global__ __launch_bounds__(256) void k_mm(const float* __restrict__ in1,
                                            const float* __restrict__ in2,
                                            const float* __restrict__ W,
                                            const float* __restrict__ bias,
                                            void* __restrict__ outv, int n) {
    constexpr int FINT = FIN1 + FIN2;
    constexpr int ROWF = FINT + 4;   // +4 floats pad
    constexpr int JPT = FOUT / 4;    // outputs per thread (32 or 16)
    constexpr int NC4 = JPT / 4;     // float4 accumulators (8 or 4)

    __shared__ float lds[64 * ROWF];

    const int t = threadIdx.x;
    const int base = blockIdx.x * 64;

    {
        constexpr int R4 = FIN1 / 4;
        const float4* g = (const float4*)in1;
        for (int i = t; i < 64 * R4; i += 256) {
            int r = i / R4, c = i % R4;
            float4 v = (base + r < n) ? g[(size_t)(base + r) * R4 + c]
                                      : make_float4(0.f, 0.f, 0.f, 0.f);
            *(float4*)&lds[r * ROWF + c * 4] = v;
        }
    }
    if constexpr (FIN2 > 0) {
        constexpr int R4 = FIN2 / 4;
        const float4* g = (const float4*)in2;
        for (int i = t; i < 64 * R4; i += 256) {
            int r = i / R4, c = i % R4;
            float4 v = (base + r < n) ? g[(size_t)(base + r) * R4 + c]
                                      : make_float4(0.f, 0.f, 0.f, 0.f);
            *(float4*)&lds[r * ROWF + FIN1 + c * 4] = v;
        }
    }
    __syncthreads();

    const int lane = t & 63;
    const int f0 = __builtin_amdgcn_readfirstlane((t >> 6) * JPT);

    float4 c0, c1, c2, c3, c4, c5, c6, c7;
    if (BIAS) {
        const float4* b4 = (const float4*)(bias + f0);
        c0 = b4[0]; c1 = b4[1]; c2 = b4[2]; c3 = b4[3];
        if (NC4 == 8) { c4 = b4[4]; c5 = b4[5]; c6 = b4[6]; c7 = b4[7]; }
        else { c4 = c5 = c6 = c7 = make_float4(0.f, 0.f, 0.f, 0.f); }
    } else {
        c0 = c1 = c2 = c3 = c4 = c5 = c6 = c7 = make_float4(0.f, 0.f, 0.f, 0.f);
    }

#define FMA_BLK(av, wp)                                                                              \
    do {                                                                                             \
        const float4* _w4 = (const float4*)(wp);                                                     \
        { float4 _t = _w4[0]; c0.x = fmaf(av, _t.x, c0.x); c0.y = fmaf(av, _t.y, c0.y);              \
          c0.z = fmaf(av, _t.z, c0.z); c0.w = fmaf(av, _t.w, c0.w); }                                \
        { float4 _t = _w4[1]; c1.x = fmaf(av, _t.x, c1.x); c1.y = fmaf(av, _t.y, c1.y);              \
          c1.z = fmaf(av, _t.z, c1.z); c1.w = fmaf(av, _t.w, c1.w); }                                \
        { float4 _t = _w4[2]; c2.x = fmaf(av, _t.x, c2.x); c2.y = fmaf(av, _t.y, c2.y);              \
          c2.z = fmaf(av, _t.z, c2.z); c2.w = fmaf(av, _t.w, c2.w); }                                \
        { float4 _t = _w4[3]; c3.x = fmaf(av, _t.x, c3.x); c3.y = fmaf(av, _t.y, c3.y);              \
          c3.z = fmaf(av, _t.z, c3.z); c3.w = fmaf(av, _t.w, c3.w); }                                \
        if constexpr (NC4 == 8) {                                                                    \
            { float4 _t = _w4[4]; c4.x = fmaf(av, _t.x, c4.x); c4.y = fmaf(av, _t.y, c4.y);          \
              c4.z = fmaf(av, _t.z, c4.z); c4.w = fmaf(av, _t.w, c4.w); }                            \
            { float4 _t = _w4[5]; c5.x = fmaf(av, _t.x, c5.x); c5.y = fmaf(av, _t.y, c5.y);          \
              c5.z = fmaf(av, _t.z, c5.z); c5.w = fmaf(av, _t.w, c5.w); }                            \
            { float4 _t = _w4[6]; c6.x = fmaf(av, _t.x, c6.x); c6.y = fmaf(av, _t.y, c6.y);          \
              c6.z = fmaf(av, _t.z, c6.z); c6.w = fmaf(av, _t.w, c6.w); }                            \
            { float4 _t = _w4[7]; c7.x = fmaf(av, _t.x, c7.x); c7.y = fmaf(av, _t.y, c7.y);          \
              c7.z = fmaf(av, _t.z, c7.z); c7.w = fmaf(av, _t.w, c7.w); }                            \
        }                                                                                            \
    } while (0)

    const float* arow = &lds[lane * ROWF];
    for (int k = 0; k < FINT; k += 4) {
        float4 a = *(const float4*)(arow + k);
        const float* wr = W + (size_t)k * FOUT + f0;
        FMA_BLK(a.x, wr);
        FMA_BLK(a.y, wr + FOUT);
        FMA_BLK(a.z, wr + 2 * FOUT);
        FMA_BLK(a.w, wr + 3 * FOUT);
    }
#undef FMA_BLK

    const int node = base + lane;
    if (node < n) {
        if (RELU) {
#define RL(c) do { c.x = fmaxf(c.x, 0.f); c.y = fmaxf(c.y, 0.f); \
                   c.z = fmaxf(c.z, 0.f); c.w = fmaxf(c.w, 0.f); } while (0)
            RL(c0); RL(c1); RL(c2); RL(c3);
            if (NC4 == 8) { RL(c4); RL(c5); RL(c6); RL(c7); }
#undef RL
        }
        if constexpr (OBF16) {
            unsigned short* orow = (unsigned short*)outv + (size_t)node * FOUT + f0;
#define ST4(i, c)                                                                  \
            do {                                                                   \
                ushort4 r;                                                         \
                r.x = bf16rne(c.x); r.y = bf16rne(c.y);                            \
                r.z = bf16rne(c.z); r.w = bf16rne(c.w);                            \
                *(ushort4*)(orow + (i) * 4) = r;                                   \
            } while (0)
            ST4(0, c0); ST4(1, c1); ST4(2, c2); ST4(3, c3);
            if (NC4 == 8) { ST4(4, c4); ST4(5, c5); ST4(6, c6); ST4(7, c7); }
#undef ST4
        } else {
            float4* orow = (float4*)((float*)outv + (size_t)node * FOUT + f0);
            orow[0] = c0; orow[1] = c1; orow[2] = c2; orow[3] = c3;
            if (NC4 == 8) { orow[4] = c4; orow[5] = c5; orow[6] = c6; orow[7] = c7; }
        }
    }
}

// ---------------- GCN aggregation (bf16 rows, fp32 accumulate) --------------
// out[i] = sum_j hW[ssrc[j]] * (dis[ssrc[j]]*dis[i])   (sorted CSR order)
//        + hW[i]*dis[i]^2 + bias   (optional relu)

template <int F, bool RELU>
__global__ __launch_bounds__(256) void k_agg(const unsigned short* __restrict__ hW,
                                             const float* __restrict__ bias,
                                             const float* __restrict__ dis,
                                             const int* __restrict__ offs,
                                             const int* __restrict__ ssrc,
                                             float* __restrict__ out, int n) {
    const int wv = threadIdx.x >> 6;
    const int lane = threadIdx.x & 63;
    const int node = blockIdx.x * 4 + wv;
    if (node >= n) return;

    constexpr int FPL = F / 64;  // bf16 per lane (1 or 2)
    const int jb = offs[node];
    const int je = offs[node + 1];
    const float di = dis[node];
    const unsigned short* lbase = hW + lane * FPL;

    float accx = 0.f, accy = 0.f;
    int j = jb;
    for (; j + 8 <= je; j += 8) {
        int s[8];
#pragma unroll
        for (int k = 0; k < 8; k++) s[k] = ssrc[j + k];
        float w[8];
#pragma unroll
        for (int k = 0; k < 8; k++) w[k] = dis[s[k]] * di;
        float hx[8], hy[8];
#pragma unroll
        for (int k = 0; k < 8; k++) {
            if constexpr (FPL == 2) {
                unsigned v = *(const unsigned*)(lbase + (size_t)s[k] * F);
                hx[k] = __uint_as_float(v << 16);
                hy[k] = __uint_as_float(v & 0xffff0000u);
            } else {
                hx[k] = bf16tof(lbase[(size_t)s[k] * F]);
            }
        }
#pragma unroll
        for (int k = 0; k < 8; k++) {
            accx = fmaf(hx[k], w[k], accx);
            if constexpr (FPL == 2) accy = fmaf(hy[k], w[k], accy);
        }
    }
    for (; j < je; j++) {
        int s = ssrc[j];
        float w = dis[s] * di;
        if constexpr (FPL == 2) {
            unsigned v = *(const unsigned*)(lbase + (size_t)s * F);
            accx = fmaf(__uint_as_float(v << 16), w, accx);
            accy = fmaf(__uint_as_float(v & 0xffff0000u), w, accy);
        } else {
            accx = fmaf(bf16tof(lbase[(size_t)s * F]), w, accx);
        }
    }

    const float sw = di * di;
    if constexpr (FPL == 2) {
        unsigned v = *(const unsigned*)(hW + (size_t)node * F + lane * 2);
        float hsx = __uint_as_float(v << 16);
        float hsy = __uint_as_float(v & 0xffff0000u);
        float2 bb = *(const float2*)(bias + lane * 2);
        float vx = accx + hsx * sw + bb.x;
        float vy = accy + hsy * sw + bb.y;
        if (RELU) { vx = fmaxf(vx, 0.f); vy = fmaxf(vy, 0.f); }
        *(float2*)(out + (size_t)node * F + lane * 2) = make_float2(vx, vy);
    } else {
        float hs = bf16tof(hW[(size_t)node * F + lane]);
        float v = accx + hs * sw + bias[lane];
        if (RELU) v = fmaxf(v, 0.f);
        out[(size_t)node * F + lane] = v;
    }
}

// ---------------- launch -----------------------------------------------------

extern "C" void kernel_launch(void* const* d_in, const int* in_sizes, int n_in,
                              void* d_out, int out_size, void* d_ws, size_t ws_size,
                              hipStream_t stream) {
    const float* x   = (const float*)d_in[0];
    const float* st  = (const float*)d_in[1];
    const int*   src = (const int*)d_in[2];
    const int*   dst = (const int*)d_in[3];
    const float* W1  = (const float*)d_in[4];
    const float* b1  = (const float*)d_in[5];
    const float* W2  = (const float*)d_in[6];
    const float* b2  = (const float*)d_in[7];
    const float* Wg0 = (const float*)d_in[8];
    const float* bg0 = (const float*)d_in[9];
    const float* Wg1 = (const float*)d_in[10];
    const float* bg1 = (const float*)d_in[11];
    const float* Wg2 = (const float*)d_in[12];
    const float* bg2 = (const float*)d_in[13];

    const int n = in_sizes[0] / 64;  // IN_DIM = 64
    const int e = in_sizes[2];
    const int nb = (n + 255) >> 8;   // coarse buckets (<=512 for n<=131072)

    char* wp = (char*)d_ws;
    auto carve = [&](size_t bytes) {
        void* p = (void*)wp;
        wp += (bytes + 255) & ~(size_t)255;
        return p;
    };
    int*   ghist = (int*)carve(512 * 4);
    int*   gcur  = (int*)carve(512 * 4);
    int*   bbase = (int*)carve(513 * 4);
    int*   offs  = (int*)carve((size_t)(n + 1) * 4);
    float* dis   = (float*)carve((size_t)n * 4);
    int*   ssrc  = (int*)carve((size_t)e * 4);
    float* bufA  = (float*)carve((size_t)n * 128 * 4);
    float* bufB  = (float*)carve((size_t)n * 128 * 4);

    // aliases: ep (edge pairs) uses bufB (dead until mm2); P (bf16 n x 128)
    // lives in d_out (dead until agg3); Q (bf16 n x 64) aliases bufA.
    int2* ep = (int2*)bufB;
    unsigned short* P = (unsigned short*)d_out;
    unsigned short* Q = (unsigned short*)bufA;

    hipMemsetAsync(ghist, 0, 512 * 4, stream);

    const int gN = (n + 255) / 256;
    const int gN64 = (n + 63) / 64;
    const int gAgg = (n + 3) / 4;
    const int gE4k = (e + 4095) / 4096;

    // graph prep: bucketed CSR build + per-bucket sort (deterministic)
    k_hist<<<gE4k, 256, 0, stream>>>(dst, e, nb, ghist);
    k_scan<<<1, 512, 0, stream>>>(ghist, nb, e, n, bbase, gcur, offs);
    k_scatter1<<<gE4k, 256, 0, stream>>>(src, dst, e, nb, gcur, ep);
    k_build<<<nb, 256, 0, stream>>>(ep, bbase, n, offs, ssrc);
    k_dis<<<gN, 256, 0, stream>>>(offs, dis, n);
    k_sort<<<gAgg, 256, 0, stream>>>(offs, ssrc, n);

    // MLP
    k_mm<64, 32, 128, true, true, false><<<gN64, 256, 0, stream>>>(x, st, W1, b1, bufA, n);
    k_mm<128, 0, 64, true, true, false><<<gN64, 256, 0, stream>>>(bufA, nullptr, W2, b2, bufB, n);  // h0

    // conv0: mm (bf16 out) -> agg@128 (bias+relu fused)
    k_mm<64, 0, 128, false, false, true><<<gN64, 256, 0, stream>>>(bufB, nullptr, Wg0, nullptr, P, n);
    k_agg<128, true><<<gAgg, 256, 0, stream>>>(P, bg0, dis, offs, ssrc, bufA, n);  // h1

    // conv1: mm (bf16 out) -> agg@128 (bias+relu fused)
    k_mm<128, 0, 128, false, false, true><<<gN64, 256, 0, stream>>>(bufA, nullptr, Wg1, nullptr, P, n);
    k_agg<128, true><<<gAgg, 256, 0, stream>>>(P, bg1, dis, offs, ssrc, bufB, n);  // h2

    // conv2: mm (bf16 out) -> agg@64 (bias, no relu) -> d_out
    k_mm<128, 0, 64, false, false, true><<<gN64, 256, 0, stream>>>(bufB, nullptr, Wg2, nullptr, Q, n);
    k_agg<64, false><<<gAgg, 256, 0, stream>>>(Q, bg2, dis, offs, ssrc, (float*)d_out, n);
}

// Round 10
// 594.272 us; speedup vs baseline: 1.8428x; 1.0965x over previous
//
#include <hip/hip_runtime.h>

// Pipeline (R3/R6 order; R8 bf16 gather rows; R9 bucketed CSR; R10 paired agg):
//   A = relu([x|st]@W1+b1)            [N,128]  mm1
//   B = relu(A@W2+b2)                 [N,64]   mm2 (h0)
//   P = bf16(B@Wg0)                   [N,128]  mm3 (P staged in d_out region)
//   A = relu(agg(P) + bg0)            [N,128]  agg1 (h1, fp32)
//   P = bf16(A@Wg1)                   [N,128]  mm4
//   B = relu(agg(P) + bg1)            [N,128]  agg2 (h2, fp32)
//   Q = bf16(B@Wg2)                   [N,64]   mm5 (Q aliases bufA)
//   out = agg(Q) + bg2                [N,64]   agg3 -> d_out
//
// R9 lesson: agg is VMEM-instruction/latency bound (FETCH 90MB, 17.6% HBM,
// VALUBusy 32%) — each edge cost a whole wave-instr for a 4B/lane row read.
// R10: half-wave edge pairing — lanes 0-31 even-offset edges, 32-63 odd;
// dwordx2/lane covers 2 rows per VMEM instr; shfl_xor(32) fold (even-sum +
// odd-sum, sorted order -> deterministic). k_dis folded into k_build.

__device__ __forceinline__ unsigned short bf16rne(float f) {
    unsigned u = __float_as_uint(f);
    unsigned r = (u + 0x7fffu + ((u >> 16) & 1u)) >> 16;
    return (unsigned short)r;
}
__device__ __forceinline__ float bf16lo(unsigned v) { return __uint_as_float(v << 16); }
__device__ __forceinline__ float bf16hi(unsigned v) { return __uint_as_float(v & 0xffff0000u); }

// ---------------- graph preprocessing: bucketed CSR (dst>>8 buckets) --------
// NB = ceil(n/256) buckets (<=512 for n<=131072).

__global__ __launch_bounds__(256) void k_hist(const int* __restrict__ dst, int e, int nb,
                                              int* __restrict__ gh) {
    __shared__ int h[512];
    const int t = threadIdx.x;
    h[t] = 0; h[t + 256] = 0;
    __syncthreads();
    const int base = blockIdx.x * 4096;
    const int end = min(base + 4096, e);
    for (int i = base + t; i < end; i += 256) atomicAdd(&h[dst[i] >> 8], 1);
    __syncthreads();
    for (int b = t; b < nb; b += 256)
        if (h[b]) atomicAdd(&gh[b], h[b]);
}

// 1 block, 512 threads: exclusive scan of gh[0..nb) -> bbase, init gcur=bbase,
// bbase[nb]=e, offs[n]=e.
__global__ __launch_bounds__(512) void k_scan(const int* __restrict__ gh, int nb, int e, int n,
                                              int* __restrict__ bbase, int* __restrict__ gcur,
                                              int* __restrict__ offs) {
    __shared__ int sm[512];
    const int t = threadIdx.x;
    int v = (t < nb) ? gh[t] : 0;
    sm[t] = v;
    __syncthreads();
    for (int off = 1; off < 512; off <<= 1) {
        int add = (t >= off) ? sm[t - off] : 0;
        __syncthreads();
        sm[t] += add;
        __syncthreads();
    }
    if (t < nb) {
        int excl = sm[t] - v;
        bbase[t] = excl;
        gcur[t] = excl;
    }
    if (t == 0) { bbase[nb] = e; offs[n] = e; }
}

// Block bins 4096 edges by bucket in LDS, reserves one contiguous chunk per
// (block,bucket) via a single global atomicAdd, writes (src,dst) pairs densely.
__global__ __launch_bounds__(256) void k_scatter1(const int* __restrict__ src,
                                                  const int* __restrict__ dst, int e, int nb,
                                                  int* __restrict__ gcur,
                                                  int2* __restrict__ ep) {
    __shared__ int h[512];
    __shared__ int cbase[512];
    const int t = threadIdx.x;
    h[t] = 0; h[t + 256] = 0;
    __syncthreads();
    const int base = blockIdx.x * 4096;
    const int end = min(base + 4096, e);
    for (int i = base + t; i < end; i += 256) atomicAdd(&h[dst[i] >> 8], 1);
    __syncthreads();
    for (int b = t; b < nb; b += 256) {
        int c = h[b];
        cbase[b] = c ? atomicAdd(&gcur[b], c) : 0;
        h[b] = 0;
    }
    __syncthreads();
    for (int i = base + t; i < end; i += 256) {
        int d = dst[i];
        int bn = d >> 8;
        int r = atomicAdd(&h[bn], 1);
        ep[cbase[bn] + r] = make_int2(src[i], d);
    }
}

// One block per bucket: per-node count + scan -> offs (coalesced); place ssrc
// within the bucket's contiguous region (L2-hot); dis computed here (folded).
__global__ __launch_bounds__(256) void k_build(const int2* __restrict__ ep,
                                               const int* __restrict__ bbase, int n,
                                               int* __restrict__ offs,
                                               int* __restrict__ ssrc,
                                               float* __restrict__ dis) {
    __shared__ int cnt[256];
    __shared__ int sm[256];
    __shared__ int cur[256];
    const int t = threadIdx.x;
    const int b = blockIdx.x;
    const int lo = bbase[b];
    const int hi = bbase[b + 1];
    cnt[t] = 0;
    __syncthreads();
    for (int i = lo + t; i < hi; i += 256) atomicAdd(&cnt[ep[i].y & 255], 1);
    __syncthreads();
    int v = cnt[t];
    sm[t] = v;
    __syncthreads();
    for (int off = 1; off < 256; off <<= 1) {
        int add = (t >= off) ? sm[t - off] : 0;
        __syncthreads();
        sm[t] += add;
        __syncthreads();
    }
    const int excl = sm[t] - v;
    const int node = (b << 8) + t;
    if (node < n) {
        offs[node] = lo + excl;
        dis[node] = rsqrtf(1.0f + (float)v);
    }
    cur[t] = lo + excl;
    __syncthreads();
    for (int i = lo + t; i < hi; i += 256) {
        int2 p = ep[i];
        int pos = atomicAdd(&cur[p.y & 255], 1);
        ssrc[pos] = p.x;
    }
}

// Sort each CSR bucket ascending -> bitwise-deterministic aggregation.
__global__ __launch_bounds__(256) void k_sort(const int* __restrict__ offs,
                                              int* __restrict__ ssrc, int n) {
    const int wv = threadIdx.x >> 6;
    const int lane = threadIdx.x & 63;
    const int node = blockIdx.x * 4 + wv;
    if (node >= n) return;
    const int jb = offs[node];
    const int je = offs[node + 1];
    const int len = je - jb;
    if (len <= 1) return;
    if (len <= 64) {
        int v = (lane < len) ? ssrc[jb + lane] : 0x7fffffff;
#pragma unroll
        for (int k = 2; k <= 64; k <<= 1) {
            for (int j = k >> 1; j > 0; j >>= 1) {
                int p = __shfl_xor(v, j);
                bool lower = (lane & j) == 0;
                bool asc = (lane & k) == 0;
                v = (lower == asc) ? min(v, p) : max(v, p);
            }
        }
        if (lane < len) ssrc[jb + lane] = v;
    } else if (lane == 0) {
        for (int a = jb + 1; a < je; a++) {
            int key = ssrc[a];
            int b = a - 1;
            while (b >= jb && ssrc[b] > key) { ssrc[b + 1] = ssrc[b]; b--; }
            ssrc[b + 1] = key;
        }
    }
}

// ---------------- dense matmul: out[n,FOUT] = [in1|in2] @ W -----------------
// Block = 64 nodes x FOUT. 256 threads = 4 f-slices x 64 lanes (lane = node).
// A-tile staged in LDS (coalesced float4); W addresses wave-uniform -> s_load.
// OBF16: epilogue rounds outputs to bf16 (RNE) and stores packed ushort4.

template <int FIN1, int FIN2, int FOUT, bool BIAS, bool RELU, bool OBF16>
__global__ __launch_bounds__(256) void k_mm(const float* __restrict__ in1,
                                            const float* __restrict__ in2,
                                            const float* __restrict__ W,
                                            const float* __restrict__ bias,
                                            void* __restrict__ outv, int n) {
    constexpr int FINT = FIN1 + FIN2;
    constexpr int ROWF = FINT + 4;   // +4 floats pad
    constexpr int JPT = FOUT / 4;    // outputs per thread (32 or 16)
    constexpr int NC4 = JPT / 4;     // float4 accumulators (8 or 4)

    __shared__ float lds[64 * ROWF];

    const int t = threadIdx.x;
    const int base = blockIdx.x * 64;

    {
        constexpr int R4 = FIN1 / 4;
        const float4* g = (const float4*)in1;
        for (int i = t; i < 64 * R4; i += 256) {
            int r = i / R4, c = i % R4;
            float4 v = (base + r < n) ? g[(size_t)(base + r) * R4 + c]
                                      : make_float4(0.f, 0.f, 0.f, 0.f);
            *(float4*)&lds[r * ROWF + c * 4] = v;
        }
    }
    if constexpr (FIN2 > 0) {
        constexpr int R4 = FIN2 / 4;
        const float4* g = (const float4*)in2;
        for (int i = t; i < 64 * R4; i += 256) {
            int r = i / R4, c = i % R4;
            float4 v = (base + r < n) ? g[(size_t)(base + r) * R4 + c]
                                      : make_float4(0.f, 0.f, 0.f, 0.f);
            *(float4*)&lds[r * ROWF + FIN1 + c * 4] = v;
        }
    }
    __syncthreads();

    const int lane = t & 63;
    const int f0 = __builtin_amdgcn_readfirstlane((t >> 6) * JPT);

    float4 c0, c1, c2, c3, c4, c5, c6, c7;
    if (BIAS) {
        const float4* b4 = (const float4*)(bias + f0);
        c0 = b4[0]; c1 = b4[1]; c2 = b4[2]; c3 = b4[3];
        if (NC4 == 8) { c4 = b4[4]; c5 = b4[5]; c6 = b4[6]; c7 = b4[7]; }
        else { c4 = c5 = c6 = c7 = make_float4(0.f, 0.f, 0.f, 0.f); }
    } else {
        c0 = c1 = c2 = c3 = c4 = c5 = c6 = c7 = make_float4(0.f, 0.f, 0.f, 0.f);
    }

#define FMA_BLK(av, wp)                                                                              \
    do {                                                                                             \
        const float4* _w4 = (const float4*)(wp);                                                     \
        { float4 _t = _w4[0]; c0.x = fmaf(av, _t.x, c0.x); c0.y = fmaf(av, _t.y, c0.y);              \
          c0.z = fmaf(av, _t.z, c0.z); c0.w = fmaf(av, _t.w, c0.w); }                                \
        { float4 _t = _w4[1]; c1.x = fmaf(av, _t.x, c1.x); c1.y = fmaf(av, _t.y, c1.y);              \
          c1.z = fmaf(av, _t.z, c1.z); c1.w = fmaf(av, _t.w, c1.w); }                                \
        { float4 _t = _w4[2]; c2.x = fmaf(av, _t.x, c2.x); c2.y = fmaf(av, _t.y, c2.y);              \
          c2.z = fmaf(av, _t.z, c2.z); c2.w = fmaf(av, _t.w, c2.w); }                                \
        { float4 _t = _w4[3]; c3.x = fmaf(av, _t.x, c3.x); c3.y = fmaf(av, _t.y, c3.y);              \
          c3.z = fmaf(av, _t.z, c3.z); c3.w = fmaf(av, _t.w, c3.w); }                                \
        if constexpr (NC4 == 8) {                                                                    \
            { float4 _t = _w4[4]; c4.x = fmaf(av, _t.x, c4.x); c4.y = fmaf(av, _t.y, c4.y);          \
              c4.z = fmaf(av, _t.z, c4.z); c4.w = fmaf(av, _t.w, c4.w); }                            \
            { float4 _t = _w4[5]; c5.x = fmaf(av, _t.x, c5.x); c5.y = fmaf(av, _t.y, c5.y);          \
              c5.z = fmaf(av, _t.z, c5.z); c5.w = fmaf(av, _t.w, c5.w); }                            \
            { float4 _t = _w4[6]; c6.x = fmaf(av, _t.x, c6.x); c6.y = fmaf(av, _t.y, c6.y);          \
              c6.z = fmaf(av, _t.z, c6.z); c6.w = fmaf(av, _t.w, c6.w); }                            \
            { float4 _t = _w4[7]; c7.x = fmaf(av, _t.x, c7.x); c7.y = fmaf(av, _t.y, c7.y);          \
              c7.z = fmaf(av, _t.z, c7.z); c7.w = fmaf(av, _t.w, c7.w); }                            \
        }                                                                                            \
    } while (0)

    const float* arow = &lds[lane * ROWF];
    for (int k = 0; k < FINT; k += 4) {
        float4 a = *(const float4*)(arow + k);
        const float* wr = W + (size_t)k * FOUT + f0;
        FMA_BLK(a.x, wr);
        FMA_BLK(a.y, wr + FOUT);
        FMA_BLK(a.z, wr + 2 * FOUT);
        FMA_BLK(a.w, wr + 3 * FOUT);
    }
#undef FMA_BLK

    const int node = base + lane;
    if (node < n) {
        if (RELU) {
#define RL(c) do { c.x = fmaxf(c.x, 0.f); c.y = fmaxf(c.y, 0.f); \
                   c.z = fmaxf(c.z, 0.f); c.w = fmaxf(c.w, 0.f); } while (0)
            RL(c0); RL(c1); RL(c2); RL(c3);
            if (NC4 == 8) { RL(c4); RL(c5); RL(c6); RL(c7); }
#undef RL
        }
        if constexpr (OBF16) {
            unsigned short* orow = (unsigned short*)outv + (size_t)node * FOUT + f0;
#define ST4(i, c)                                                                  \
            do {                                                                   \
                ushort4 r;                                                         \
                r.x = bf16rne(c.x); r.y = bf16rne(c.y);                            \
                r.z = bf16rne(c.z); r.w = bf16rne(c.w);                            \
                *(ushort4*)(orow + (i) * 4) = r;                                   \
            } while (0)
            ST4(0, c0); ST4(1, c1); ST4(2, c2); ST4(3, c3);
            if (NC4 == 8) { ST4(4, c4); ST4(5, c5); ST4(6, c6); ST4(7, c7); }
#undef ST4
        } else {
            float4* orow = (float4*)((float*)outv + (size_t)node * FOUT + f0);
            orow[0] = c0; orow[1] = c1; orow[2] = c2; orow[3] = c3;
            if (NC4 == 8) { orow[4] = c4; orow[5] = c5; orow[6] = c6; orow[7] = c7; }
        }
    }
}

// ---------------- GCN aggregation (bf16 rows, half-wave edge pairing) -------
// out[i] = (sum over even-offset edges) + (sum over odd-offset edges)
//        + hW[i]*dis[i]^2 + bias   (each half in sorted CSR order -> determ.)
// Lanes 0-31 process even-offset edges, 32-63 odd; each lane loads FPL=F/32
// bf16 per row (dwordx2 for F=128, dword for F=64) -> one VMEM instruction
// fetches TWO full rows. Fold with one shfl_xor(32).

template <int F, bool RELU>
__global__ __launch_bounds__(256) void k_agg(const unsigned short* __restrict__ hW,
                                             const float* __restrict__ bias,
                                             const float* __restrict__ dis,
                                             const int* __restrict__ offs,
                                             const int* __restrict__ ssrc,
                                             float* __restrict__ out, int n) {
    constexpr int FPL = F / 32;          // bf16 per lane: 4 (F=128) or 2 (F=64)
    const int wv = threadIdx.x >> 6;
    const int lane = threadIdx.x & 63;
    const int node = blockIdx.x * 4 + wv;
    if (node >= n) return;
    const int g = lane >> 5;             // which edge of the pair (0=even,1=odd)
    const int hl = lane & 31;
    const int jb = offs[node];
    const int je = offs[node + 1];
    const float di = dis[node];

    float a0 = 0.f, a1 = 0.f, a2 = 0.f, a3 = 0.f;
    const unsigned short* lbase = hW + hl * FPL;

#define ROW_FMA(sidx, wgt)                                                          \
    do {                                                                            \
        if constexpr (FPL == 4) {                                                   \
            uint2 rv = *(const uint2*)(lbase + (size_t)(sidx) * F);                 \
            a0 = fmaf(bf16lo(rv.x), (wgt), a0);                                     \
            a1 = fmaf(bf16hi(rv.x), (wgt), a1);                                     \
            a2 = fmaf(bf16lo(rv.y), (wgt), a2);                                     \
            a3 = fmaf(bf16hi(rv.y), (wgt), a3);                                     \
        } else {                                                                    \
            unsigned rv = *(const unsigned*)(lbase + (size_t)(sidx) * F);           \
            a0 = fmaf(bf16lo(rv), (wgt), a0);                                       \
            a1 = fmaf(bf16hi(rv), (wgt), a1);                                       \
        }                                                                           \
    } while (0)

    int j = jb;
    // batches of 4 pairs (8 edges)
    for (; j + 8 <= je; j += 8) {
        int sv = ssrc[j + (lane & 7)];
        int s0 = __shfl(sv, 0 + g);
        int s1 = __shfl(sv, 2 + g);
        int s2 = __shfl(sv, 4 + g);
        int s3 = __shfl(sv, 6 + g);
        float w0 = dis[s0] * di;
        float w1 = dis[s1] * di;
        float w2 = dis[s2] * di;
        float w3 = dis[s3] * di;
        ROW_FMA(s0, w0);
        ROW_FMA(s1, w1);
        ROW_FMA(s2, w2);
        ROW_FMA(s3, w3);
    }
    // leftover full pairs
    for (; j + 2 <= je; j += 2) {
        int s = ssrc[j + g];
        float w = dis[s] * di;
        ROW_FMA(s, w);
    }
    // tail single edge (even offset -> low half active)
    if (j < je) {
        int st = ssrc[j];
        bool act = (g == 0);
        int se = act ? st : node;
        float w = act ? dis[st] * di : 0.f;
        ROW_FMA(se, w);
    }
#undef ROW_FMA

    // fold halves: even-sum + odd-sum (both halves end with the total)
    a0 += __shfl_xor(a0, 32);
    a1 += __shfl_xor(a1, 32);
    if constexpr (FPL == 4) {
        a2 += __shfl_xor(a2, 32);
        a3 += __shfl_xor(a3, 32);
    }

    if (g == 0) {
        const float sw = di * di;
        if constexpr (FPL == 4) {
            uint2 sv = *(const uint2*)(hW + (size_t)node * F + hl * 4);
            float4 bb = *(const float4*)(bias + hl * 4);
            float v0 = a0 + bf16lo(sv.x) * sw + bb.x;
            float v1 = a1 + bf16hi(sv.x) * sw + bb.y;
            float v2 = a2 + bf16lo(sv.y) * sw + bb.z;
            float v3 = a3 + bf16hi(sv.y) * sw + bb.w;
            if (RELU) {
                v0 = fmaxf(v0, 0.f); v1 = fmaxf(v1, 0.f);
                v2 = fmaxf(v2, 0.f); v3 = fmaxf(v3, 0.f);
            }
            *(float4*)(out + (size_t)node * F + hl * 4) = make_float4(v0, v1, v2, v3);
        } else {
            unsigned sv = *(const unsigned*)(hW + (size_t)node * F + hl * 2);
            float2 bb = *(const float2*)(bias + hl * 2);
            float v0 = a0 + bf16lo(sv) * sw + bb.x;
            float v1 = a1 + bf16hi(sv) * sw + bb.y;
            if (RELU) { v0 = fmaxf(v0, 0.f); v1 = fmaxf(v1, 0.f); }
            *(float2*)(out + (size_t)node * F + hl * 2) = make_float2(v0, v1);
        }
    }
}

// ---------------- launch -----------------------------------------------------

extern "C" void kernel_launch(void* const* d_in, const int* in_sizes, int n_in,
                              void* d_out, int out_size, void* d_ws, size_t ws_size,
                              hipStream_t stream) {
    const float* x   = (const float*)d_in[0];
    const float* st  = (const float*)d_in[1];
    const int*   src = (const int*)d_in[2];
    const int*   dst = (const int*)d_in[3];
    const float* W1  = (const float*)d_in[4];
    const float* b1  = (const float*)d_in[5];
    const float* W2  = (const float*)d_in[6];
    const float* b2  = (const float*)d_in[7];
    const float* Wg0 = (const float*)d_in[8];
    const float* bg0 = (const float*)d_in[9];
    const float* Wg1 = (const float*)d_in[10];
    const float* bg1 = (const float*)d_in[11];
    const float* Wg2 = (const float*)d_in[12];
    const float* bg2 = (const float*)d_in[13];

    const int n = in_sizes[0] / 64;  // IN_DIM = 64
    const int e = in_sizes[2];
    const int nb = (n + 255) >> 8;   // coarse buckets (<=512 for n<=131072)

    char* wp = (char*)d_ws;
    auto carve = [&](size_t bytes) {
        void* p = (void*)wp;
        wp += (bytes + 255) & ~(size_t)255;
        return p;
    };
    int*   ghist = (int*)carve(512 * 4);
    int*   gcur  = (int*)carve(512 * 4);
    int*   bbase = (int*)carve(513 * 4);
    int*   offs  = (int*)carve((size_t)(n + 1) * 4);
    float* dis   = (float*)carve((size_t)n * 4);
    int*   ssrc  = (int*)carve((size_t)e * 4);
    float* bufA  = (float*)carve((size_t)n * 128 * 4);
    float* bufB  = (float*)carve((size_t)n * 128 * 4);

    // aliases: ep (edge pairs) uses bufB (dead until mm2); P (bf16 n x 128)
    // lives in d_out (dead until agg3); Q (bf16 n x 64) aliases bufA.
    int2* ep = (int2*)bufB;
    unsigned short* P = (unsigned short*)d_out;
    unsigned short* Q = (unsigned short*)bufA;

    hipMemsetAsync(ghist, 0, 512 * 4, stream);

    const int gN64 = (n + 63) / 64;
    const int gAgg = (n + 3) / 4;
    const int gE4k = (e + 4095) / 4096;

    // graph prep: bucketed CSR build + per-bucket sort (deterministic)
    k_hist<<<gE4k, 256, 0, stream>>>(dst, e, nb, ghist);
    k_scan<<<1, 512, 0, stream>>>(ghist, nb, e, n, bbase, gcur, offs);
    k_scatter1<<<gE4k, 256, 0, stream>>>(src, dst, e, nb, gcur, ep);
    k_build<<<nb, 256, 0, stream>>>(ep, bbase, n, offs, ssrc, dis);
    k_sort<<<gAgg, 256, 0, stream>>>(offs, ssrc, n);

    // MLP
    k_mm<64, 32, 128, true, true, false><<<gN64, 256, 0, stream>>>(x, st, W1, b1, bufA, n);
    k_mm<128, 0, 64, true, true, false><<<gN64, 256, 0, stream>>>(bufA, nullptr, W2, b2, bufB, n);  // h0

    // conv0: mm (bf16 out) -> agg@128 (bias+relu fused)
    k_mm<64, 0, 128, false, false, true><<<gN64, 256, 0, stream>>>(bufB, nullptr, Wg0, nullptr, P, n);
    k_agg<128, true><<<gAgg, 256, 0, stream>>>(P, bg0, dis, offs, ssrc, bufA, n);  // h1

    // conv1: mm (bf16 out) -> agg@128 (bias+relu fused)
    k_mm<128, 0, 128, false, false, true><<<gN64, 256, 0, stream>>>(bufA, nullptr, Wg1, nullptr, P, n);
    k_agg<128, true><<<gAgg, 256, 0, stream>>>(P, bg1, dis, offs, ssrc, bufB, n);  // h2

    // conv2: mm (bf16 out) -> agg@64 (bias, no relu) -> d_out
    k_mm<128, 0, 64, false, false, true><<<gN64, 256, 0, stream>>>(bufB, nullptr, Wg2, nullptr, Q, n);
    k_agg<64, false><<<gAgg, 256, 0, stream>>>(Q, bg2, dis, offs, ssrc, (float*)d_out, n);
}

// Round 12
// 507.909 us; speedup vs baseline: 2.1562x; 1.1700x over previous
//
#include <hip/hip_runtime.h>

// Pipeline (R3/R6 order; R8 bf16 gathers; R9 bucketed CSR; R10 paired agg;
// R11/R12 MFMA conv matmuls + bf16 intermediates h0/h1/h2):
//   A = relu([x|st]@W1+b1)            [N,128]  mm1 (fp32 VALU)
//   h0 = bf16(relu(A@W2+b2))          [N,64]   mm2 (fp32 VALU, bf16 out)
//   P = bf16(h0@Wg0)                  [N,128]  mmx3 (MFMA, P in d_out region)
//   h1 = bf16(relu(agg(P) + bg0))     [N,128]  agg1
//   P = bf16(h1@Wg1)                  [N,128]  mmx4 (MFMA)
//   h2 = bf16(relu(agg(P) + bg1))     [N,128]  agg2
//   Q = bf16(h2@Wg2)                  [N,64]   mmx5 (MFMA)
//   out = agg(Q) + bg2                [N,64]   agg3 -> d_out (fp32)
//
// R11 lesson: k_wprep was launched with K*FOUT/2 threads (16/32 typo) ->
// half of every Wf buffer stayed 0xAA-poison (~0 in bf16) -> absmax 0.63.
// R12 = R11 with corrected wprep grids ((K*FOUT+255)/256 blocks).
// MFMA layouts (guide-verified): A[m=lane&15][k=(lane>>4)*8+j], B mirrored
// (B[k=(lane>>4)*8+j][col=lane&15]), C/D[row=(lane>>4)*4+reg][col=lane&15].

__device__ __forceinline__ unsigned short bf16rne(float f) {
    unsigned u = __float_as_uint(f);
    unsigned r = (u + 0x7fffu + ((u >> 16) & 1u)) >> 16;
    return (unsigned short)r;
}
__device__ __forceinline__ float bf16lo(unsigned v) { return __uint_as_float(v << 16); }
__device__ __forceinline__ float bf16hi(unsigned v) { return __uint_as_float(v & 0xffff0000u); }

using bf16x8 = __attribute__((ext_vector_type(8))) short;
using f32x4  = __attribute__((ext_vector_type(4))) float;

// ---------------- graph preprocessing: bucketed CSR (dst>>8 buckets) --------

__global__ __launch_bounds__(256) void k_hist(const int* __restrict__ dst, int e, int nb,
                                              int* __restrict__ gh) {
    __shared__ int h[512];
    const int t = threadIdx.x;
    h[t] = 0; h[t + 256] = 0;
    __syncthreads();
    const int base = blockIdx.x * 4096;
    const int end = min(base + 4096, e);
    for (int i = base + t; i < end; i += 256) atomicAdd(&h[dst[i] >> 8], 1);
    __syncthreads();
    for (int b = t; b < nb; b += 256)
        if (h[b]) atomicAdd(&gh[b], h[b]);
}

__global__ __launch_bounds__(512) void k_scan(const int* __restrict__ gh, int nb, int e, int n,
                                              int* __restrict__ bbase, int* __restrict__ gcur,
                                              int* __restrict__ offs) {
    __shared__ int sm[512];
    const int t = threadIdx.x;
    int v = (t < nb) ? gh[t] : 0;
    sm[t] = v;
    __syncthreads();
    for (int off = 1; off < 512; off <<= 1) {
        int add = (t >= off) ? sm[t - off] : 0;
        __syncthreads();
        sm[t] += add;
        __syncthreads();
    }
    if (t < nb) {
        int excl = sm[t] - v;
        bbase[t] = excl;
        gcur[t] = excl;
    }
    if (t == 0) { bbase[nb] = e; offs[n] = e; }
}

__global__ __launch_bounds__(256) void k_scatter1(const int* __restrict__ src,
                                                  const int* __restrict__ dst, int e, int nb,
                                                  int* __restrict__ gcur,
                                                  int2* __restrict__ ep) {
    __shared__ int h[512];
    __shared__ int cbase[512];
    const int t = threadIdx.x;
    h[t] = 0; h[t + 256] = 0;
    __syncthreads();
    const int base = blockIdx.x * 4096;
    const int end = min(base + 4096, e);
    for (int i = base + t; i < end; i += 256) atomicAdd(&h[dst[i] >> 8], 1);
    __syncthreads();
    for (int b = t; b < nb; b += 256) {
        int c = h[b];
        cbase[b] = c ? atomicAdd(&gcur[b], c) : 0;
        h[b] = 0;
    }
    __syncthreads();
    for (int i = base + t; i < end; i += 256) {
        int d = dst[i];
        int bn = d >> 8;
        int r = atomicAdd(&h[bn], 1);
        ep[cbase[bn] + r] = make_int2(src[i], d);
    }
}

__global__ __launch_bounds__(256) void k_build(const int2* __restrict__ ep,
                                               const int* __restrict__ bbase, int n,
                                               int* __restrict__ offs,
                                               int* __restrict__ ssrc,
                                               float* __restrict__ dis) {
    __shared__ int cnt[256];
    __shared__ int sm[256];
    __shared__ int cur[256];
    const int t = threadIdx.x;
    const int b = blockIdx.x;
    const int lo = bbase[b];
    const int hi = bbase[b + 1];
    cnt[t] = 0;
    __syncthreads();
    for (int i = lo + t; i < hi; i += 256) atomicAdd(&cnt[ep[i].y & 255], 1);
    __syncthreads();
    int v = cnt[t];
    sm[t] = v;
    __syncthreads();
    for (int off = 1; off < 256; off <<= 1) {
        int add = (t >= off) ? sm[t - off] : 0;
        __syncthreads();
        sm[t] += add;
        __syncthreads();
    }
    const int excl = sm[t] - v;
    const int node = (b << 8) + t;
    if (node < n) {
        offs[node] = lo + excl;
        dis[node] = rsqrtf(1.0f + (float)v);
    }
    cur[t] = lo + excl;
    __syncthreads();
    for (int i = lo + t; i < hi; i += 256) {
        int2 p = ep[i];
        int pos = atomicAdd(&cur[p.y & 255], 1);
        ssrc[pos] = p.x;
    }
}

__global__ __launch_bounds__(256) void k_sort(const int* __restrict__ offs,
                                              int* __restrict__ ssrc, int n) {
    const int wv = threadIdx.x >> 6;
    const int lane = threadIdx.x & 63;
    const int node = blockIdx.x * 4 + wv;
    if (node >= n) return;
    const int jb = offs[node];
    const int je = offs[node + 1];
    const int len = je - jb;
    if (len <= 1) return;
    if (len <= 64) {
        int v = (lane < len) ? ssrc[jb + lane] : 0x7fffffff;
#pragma unroll
        for (int k = 2; k <= 64; k <<= 1) {
            for (int j = k >> 1; j > 0; j >>= 1) {
                int p = __shfl_xor(v, j);
                bool lower = (lane & j) == 0;
                bool asc = (lane & k) == 0;
                v = (lower == asc) ? min(v, p) : max(v, p);
            }
        }
        if (lane < len) ssrc[jb + lane] = v;
    } else if (lane == 0) {
        for (int a = jb + 1; a < je; a++) {
            int key = ssrc[a];
            int b = a - 1;
            while (b >= jb && ssrc[b] > key) { ssrc[b + 1] = ssrc[b]; b--; }
            ssrc[b + 1] = key;
        }
    }
}

// ---------------- W -> MFMA fragment-ordered bf16 ---------------------------
// Wf[((kt*CT+ct)*64+lane)*8 + j] = bf16(W[kt*32+(lane>>4)*8+j][ct*16+(lane&15)])
// One thread per bf16 element: grid must cover K*FOUT threads (R11 bug: /2).

__global__ void k_wprep(const float* __restrict__ W, unsigned short* __restrict__ Wf,
                        int K, int FOUT) {
    const int CT = FOUT / 16;
    int tid = blockIdx.x * 256 + threadIdx.x;
    int total = K * FOUT;
    if (tid >= total) return;
    int j = tid & 7;
    int lane = (tid >> 3) & 63;
    int ct = (tid >> 9) % CT;
    int kt = tid / (512 * CT);
    int k = kt * 32 + (lane >> 4) * 8 + j;
    int c = ct * 16 + (lane & 15);
    Wf[tid] = bf16rne(W[(size_t)k * FOUT + c]);
}

// ---------------- MFMA matmul: out[n,FOUT](bf16) = in[n,K](bf16) @ Wf -------
// Block = 64 nodes (4 waves x 16 rows). Wave computes 16 x FOUT via CT
// col-tiles of mfma_f32_16x16x32_bf16, KT = K/32 k-steps. No bias/relu
// (fused in the following agg).

template <int K, int FOUT>
__global__ __launch_bounds__(256) void k_mmx(const unsigned short* __restrict__ in,
                                             const unsigned short* __restrict__ Wf,
                                             unsigned short* __restrict__ out, int n) {
    constexpr int KT = K / 32;
    constexpr int CT = FOUT / 16;
    const int t = threadIdx.x;
    const int wv = t >> 6;
    const int lane = t & 63;
    const int rowBase = blockIdx.x * 64 + wv * 16;
    const int m = lane & 15;
    const int q = lane >> 4;

    f32x4 acc[CT];
#pragma unroll
    for (int c = 0; c < CT; c++) acc[c] = (f32x4){0.f, 0.f, 0.f, 0.f};

    int arow = rowBase + m;
    if (arow >= n) arow = n - 1;
    const unsigned short* ap = in + (size_t)arow * K + q * 8;
    const bf16x8* wfp = (const bf16x8*)Wf;

#pragma unroll
    for (int kt = 0; kt < KT; kt++) {
        bf16x8 a = *(const bf16x8*)(ap + kt * 32);
#pragma unroll
        for (int c = 0; c < CT; c++) {
            bf16x8 b = wfp[(kt * CT + c) * 64 + lane];
            acc[c] = __builtin_amdgcn_mfma_f32_16x16x32_bf16(a, b, acc[c], 0, 0, 0);
        }
    }

    // D[row=(lane>>4)*4+r][col=lane&15] per col-tile
    const int crow = rowBase + q * 4;
#pragma unroll
    for (int c = 0; c < CT; c++) {
#pragma unroll
        for (int r = 0; r < 4; r++) {
            int rr = crow + r;
            if (rr < n) out[(size_t)rr * FOUT + c * 16 + m] = bf16rne(acc[c][r]);
        }
    }
}

// ---------------- dense matmul (fp32 VALU, MLP only) ------------------------

template <int FIN1, int FIN2, int FOUT, bool BIAS, bool RELU, bool OBF16>
__global__ __launch_bounds__(256) void k_mm(const float* __restrict__ in1,
                                            const float* __restrict__ in2,
                                            const float* __restrict__ W,
                                            const float* __restrict__ bias,
                                            void* __restrict__ outv, int n) {
    constexpr int FINT = FIN1 + FIN2;
    constexpr int ROWF = FINT + 4;
    constexpr int JPT = FOUT / 4;
    constexpr int NC4 = JPT / 4;

    __shared__ float lds[64 * ROWF];

    const int t = threadIdx.x;
    const int base = blockIdx.x * 64;

    {
        constexpr int R4 = FIN1 / 4;
        const float4* g = (const float4*)in1;
        for (int i = t; i < 64 * R4; i += 256) {
            int r = i / R4, c = i % R4;
            float4 v = (base + r < n) ? g[(size_t)(base + r) * R4 + c]
                                      : make_float4(0.f, 0.f, 0.f, 0.f);
            *(float4*)&lds[r * ROWF + c * 4] = v;
        }
    }
    if constexpr (FIN2 > 0) {
        constexpr int R4 = FIN2 / 4;
        const float4* g = (const float4*)in2;
        for (int i = t; i < 64 * R4; i += 256) {
            int r = i / R4, c = i % R4;
            float4 v = (base + r < n) ? g[(size_t)(base + r) * R4 + c]
                                      : make_float4(0.f, 0.f, 0.f, 0.f);
            *(float4*)&lds[r * ROWF + FIN1 + c * 4] = v;
        }
    }
    __syncthreads();

    const int lane = t & 63;
    const int f0 = __builtin_amdgcn_readfirstlane((t >> 6) * JPT);

    float4 c0, c1, c2, c3, c4, c5, c6, c7;
    if (BIAS) {
        const float4* b4 = (const float4*)(bias + f0);
        c0 = b4[0]; c1 = b4[1]; c2 = b4[2]; c3 = b4[3];
        if (NC4 == 8) { c4 = b4[4]; c5 = b4[5]; c6 = b4[6]; c7 = b4[7]; }
        else { c4 = c5 = c6 = c7 = make_float4(0.f, 0.f, 0.f, 0.f); }
    } else {
        c0 = c1 = c2 = c3 = c4 = c5 = c6 = c7 = make_float4(0.f, 0.f, 0.f, 0.f);
    }

#define FMA_BLK(av, wp)                                                                              \
    do {                                                                                             \
        const float4* _w4 = (const float4*)(wp);                                                     \
        { float4 _t = _w4[0]; c0.x = fmaf(av, _t.x, c0.x); c0.y = fmaf(av, _t.y, c0.y);              \
          c0.z = fmaf(av, _t.z, c0.z); c0.w = fmaf(av, _t.w, c0.w); }                                \
        { float4 _t = _w4[1]; c1.x = fmaf(av, _t.x, c1.x); c1.y = fmaf(av, _t.y, c1.y);              \
          c1.z = fmaf(av, _t.z, c1.z); c1.w = fmaf(av, _t.w, c1.w); }                                \
        { float4 _t = _w4[2]; c2.x = fmaf(av, _t.x, c2.x); c2.y = fmaf(av, _t.y, c2.y);              \
          c2.z = fmaf(av, _t.z, c2.z); c2.w = fmaf(av, _t.w, c2.w); }                                \
        { float4 _t = _w4[3]; c3.x = fmaf(av, _t.x, c3.x); c3.y = fmaf(av, _t.y, c3.y);              \
          c3.z = fmaf(av, _t.z, c3.z); c3.w = fmaf(av, _t.w, c3.w); }                                \
        if constexpr (NC4 == 8) {                                                                    \
            { float4 _t = _w4[4]; c4.x = fmaf(av, _t.x, c4.x); c4.y = fmaf(av, _t.y, c4.y);          \
              c4.z = fmaf(av, _t.z, c4.z); c4.w = fmaf(av, _t.w, c4.w); }                            \
            { float4 _t = _w4[5]; c5.x = fmaf(av, _t.x, c5.x); c5.y = fmaf(av, _t.y, c5.y);          \
              c5.z = fmaf(av, _t.z, c5.z); c5.w = fmaf(av, _t.w, c5.w); }                            \
            { float4 _t = _w4[6]; c6.x = fmaf(av, _t.x, c6.x); c6.y = fmaf(av, _t.y, c6.y);          \
              c6.z = fmaf(av, _t.z, c6.z); c6.w = fmaf(av, _t.w, c6.w); }                            \
            { float4 _t = _w4[7]; c7.x = fmaf(av, _t.x, c7.x); c7.y = fmaf(av, _t.y, c7.y);          \
              c7.z = fmaf(av, _t.z, c7.z); c7.w = fmaf(av, _t.w, c7.w); }                            \
        }                                                                                            \
    } while (0)

    const float* arow = &lds[lane * ROWF];
    for (int k = 0; k < FINT; k += 4) {
        float4 a = *(const float4*)(arow + k);
        const float* wr = W + (size_t)k * FOUT + f0;
        FMA_BLK(a.x, wr);
        FMA_BLK(a.y, wr + FOUT);
        FMA_BLK(a.z, wr + 2 * FOUT);
        FMA_BLK(a.w, wr + 3 * FOUT);
    }
#undef FMA_BLK

    const int node = base + lane;
    if (node < n) {
        if (RELU) {
#define RL(c) do { c.x = fmaxf(c.x, 0.f); c.y = fmaxf(c.y, 0.f); \
                   c.z = fmaxf(c.z, 0.f); c.w = fmaxf(c.w, 0.f); } while (0)
            RL(c0); RL(c1); RL(c2); RL(c3);
            if (NC4 == 8) { RL(c4); RL(c5); RL(c6); RL(c7); }
#undef RL
        }
        if constexpr (OBF16) {
            unsigned short* orow = (unsigned short*)outv + (size_t)node * FOUT + f0;
#define ST4(i, c)                                                                  \
            do {                                                                   \
                ushort4 r;                                                         \
                r.x = bf16rne(c.x); r.y = bf16rne(c.y);                            \
                r.z = bf16rne(c.z); r.w = bf16rne(c.w);                            \
                *(ushort4*)(orow + (i) * 4) = r;                                   \
            } while (0)
            ST4(0, c0); ST4(1, c1); ST4(2, c2); ST4(3, c3);
            if (NC4 == 8) { ST4(4, c4); ST4(5, c5); ST4(6, c6); ST4(7, c7); }
#undef ST4
        } else {
            float4* orow = (float4*)((float*)outv + (size_t)node * FOUT + f0);
            orow[0] = c0; orow[1] = c1; orow[2] = c2; orow[3] = c3;
            if (NC4 == 8) { orow[4] = c4; orow[5] = c5; orow[6] = c6; orow[7] = c7; }
        }
    }
}

// ---------------- GCN aggregation (bf16 rows, half-wave pairing) ------------
// OB: output bf16 (for h1/h2) else fp32 (final).

template <int F, bool RELU, bool OB>
__global__ __launch_bounds__(256) void k_agg(const unsigned short* __restrict__ hW,
                                             const float* __restrict__ bias,
                                             const float* __restrict__ dis,
                                             const int* __restrict__ offs,
                                             const int* __restrict__ ssrc,
                                             void* __restrict__ outv, int n) {
    constexpr int FPL = F / 32;
    const int wv = threadIdx.x >> 6;
    const int lane = threadIdx.x & 63;
    const int node = blockIdx.x * 4 + wv;
    if (node >= n) return;
    const int g = lane >> 5;
    const int hl = lane & 31;
    const int jb = offs[node];
    const int je = offs[node + 1];
    const float di = dis[node];

    float a0 = 0.f, a1 = 0.f, a2 = 0.f, a3 = 0.f;
    const unsigned short* lbase = hW + hl * FPL;

#define ROW_FMA(sidx, wgt)                                                          \
    do {                                                                            \
        if constexpr (FPL == 4) {                                                   \
            uint2 rv = *(const uint2*)(lbase + (size_t)(sidx) * F);                 \
            a0 = fmaf(bf16lo(rv.x), (wgt), a0);                                     \
            a1 = fmaf(bf16hi(rv.x), (wgt), a1);                                     \
            a2 = fmaf(bf16lo(rv.y), (wgt), a2);                                     \
            a3 = fmaf(bf16hi(rv.y), (wgt), a3);                                     \
        } else {                                                                    \
            unsigned rv = *(const unsigned*)(lbase + (size_t)(sidx) * F);           \
            a0 = fmaf(bf16lo(rv), (wgt), a0);                                       \
            a1 = fmaf(bf16hi(rv), (wgt), a1);                                       \
        }                                                                           \
    } while (0)

    int j = jb;
    for (; j + 8 <= je; j += 8) {
        int sv = ssrc[j + (lane & 7)];
        int s0 = __shfl(sv, 0 + g);
        int s1 = __shfl(sv, 2 + g);
        int s2 = __shfl(sv, 4 + g);
        int s3 = __shfl(sv, 6 + g);
        float w0 = dis[s0] * di;
        float w1 = dis[s1] * di;
        float w2 = dis[s2] * di;
        float w3 = dis[s3] * di;
        ROW_FMA(s0, w0);
        ROW_FMA(s1, w1);
        ROW_FMA(s2, w2);
        ROW_FMA(s3, w3);
    }
    for (; j + 2 <= je; j += 2) {
        int s = ssrc[j + g];
        float w = dis[s] * di;
        ROW_FMA(s, w);
    }
    if (j < je) {
        int st = ssrc[j];
        bool act = (g == 0);
        int se = act ? st : node;
        float w = act ? dis[st] * di : 0.f;
        ROW_FMA(se, w);
    }
#undef ROW_FMA

    a0 += __shfl_xor(a0, 32);
    a1 += __shfl_xor(a1, 32);
    if constexpr (FPL == 4) {
        a2 += __shfl_xor(a2, 32);
        a3 += __shfl_xor(a3, 32);
    }

    if (g == 0) {
        const float sw = di * di;
        if constexpr (FPL == 4) {
            uint2 sv = *(const uint2*)(hW + (size_t)node * F + hl * 4);
            float4 bb = *(const float4*)(bias + hl * 4);
            float v0 = a0 + bf16lo(sv.x) * sw + bb.x;
            float v1 = a1 + bf16hi(sv.x) * sw + bb.y;
            float v2 = a2 + bf16lo(sv.y) * sw + bb.z;
            float v3 = a3 + bf16hi(sv.y) * sw + bb.w;
            if (RELU) {
                v0 = fmaxf(v0, 0.f); v1 = fmaxf(v1, 0.f);
                v2 = fmaxf(v2, 0.f); v3 = fmaxf(v3, 0.f);
            }
            if constexpr (OB) {
                ushort4 o;
                o.x = bf16rne(v0); o.y = bf16rne(v1);
                o.z = bf16rne(v2); o.w = bf16rne(v3);
                *(ushort4*)((unsigned short*)outv + (size_t)node * F + hl * 4) = o;
            } else {
                *(float4*)((float*)outv + (size_t)node * F + hl * 4) =
                    make_float4(v0, v1, v2, v3);
            }
        } else {
            unsigned sv = *(const unsigned*)(hW + (size_t)node * F + hl * 2);
            float2 bb = *(const float2*)(bias + hl * 2);
            float v0 = a0 + bf16lo(sv) * sw + bb.x;
            float v1 = a1 + bf16hi(sv) * sw + bb.y;
            if (RELU) { v0 = fmaxf(v0, 0.f); v1 = fmaxf(v1, 0.f); }
            if constexpr (OB) {
                ushort2 o;
                o.x = bf16rne(v0); o.y = bf16rne(v1);
                *(ushort2*)((unsigned short*)outv + (size_t)node * F + hl * 2) = o;
            } else {
                *(float2*)((float*)outv + (size_t)node * F + hl * 2) =
                    make_float2(v0, v1);
            }
        }
    }
}

// ---------------- launch -----------------------------------------------------

extern "C" void kernel_launch(void* const* d_in, const int* in_sizes, int n_in,
                              void* d_out, int out_size, void* d_ws, size_t ws_size,
                              hipStream_t stream) {
    const float* x   = (const float*)d_in[0];
    const float* st  = (const float*)d_in[1];
    const int*   src = (const int*)d_in[2];
    const int*   dst = (const int*)d_in[3];
    const float* W1  = (const float*)d_in[4];
    const float* b1  = (const float*)d_in[5];
    const float* W2  = (const float*)d_in[6];
    const float* b2  = (const float*)d_in[7];
    const float* Wg0 = (const float*)d_in[8];
    const float* bg0 = (const float*)d_in[9];
    const float* Wg1 = (const float*)d_in[10];
    const float* bg1 = (const float*)d_in[11];
    const float* Wg2 = (const float*)d_in[12];
    const float* bg2 = (const float*)d_in[13];

    const int n = in_sizes[0] / 64;  // IN_DIM = 64
    const int e = in_sizes[2];
    const int nb = (n + 255) >> 8;

    char* wp = (char*)d_ws;
    auto carve = [&](size_t bytes) {
        void* p = (void*)wp;
        wp += (bytes + 255) & ~(size_t)255;
        return p;
    };
    int*   ghist = (int*)carve(512 * 4);
    int*   gcur  = (int*)carve(512 * 4);
    int*   bbase = (int*)carve(513 * 4);
    int*   offs  = (int*)carve((size_t)(n + 1) * 4);
    float* dis   = (float*)carve((size_t)n * 4);
    int*   ssrc  = (int*)carve((size_t)e * 4);
    char*  R3    = (char*)carve((size_t)n * 128 * 4);  // ep -> M1 -> h1|h2
    char*  R2    = (char*)carve((size_t)n * 64 * 2);   // h0 -> Q
    unsigned short* W0f = (unsigned short*)carve((size_t)64 * 128 * 2);
    unsigned short* W1f = (unsigned short*)carve((size_t)128 * 128 * 2);
    unsigned short* W2f = (unsigned short*)carve((size_t)128 * 64 * 2);

    // aliases (stream-ordered lifetimes):
    int2* ep = (int2*)R3;                                 // dead after k_build
    float* M1 = (float*)R3;                               // mm1 out, dead after mm2
    unsigned short* h1 = (unsigned short*)R3;             // agg1 out (n*128 bf16)
    unsigned short* h2 = (unsigned short*)(R3 + (size_t)n * 128 * 2);  // agg2 out
    unsigned short* h0 = (unsigned short*)R2;             // mm2 out, dead after mmx3
    unsigned short* Q  = (unsigned short*)R2;             // mmx5 out
    unsigned short* P  = (unsigned short*)d_out;          // conv pre-agg (n*128 bf16)

    hipMemsetAsync(ghist, 0, 512 * 4, stream);

    const int gN64 = (n + 63) / 64;
    const int gAgg = (n + 3) / 4;
    const int gE4k = (e + 4095) / 4096;

    // graph prep
    k_hist<<<gE4k, 256, 0, stream>>>(dst, e, nb, ghist);
    k_scan<<<1, 512, 0, stream>>>(ghist, nb, e, n, bbase, gcur, offs);
    k_scatter1<<<gE4k, 256, 0, stream>>>(src, dst, e, nb, gcur, ep);
    k_build<<<nb, 256, 0, stream>>>(ep, bbase, n, offs, ssrc, dis);
    k_sort<<<gAgg, 256, 0, stream>>>(offs, ssrc, n);

    // W fragment prep: one thread per bf16 element = K*FOUT threads (R11 fix)
    k_wprep<<<(64 * 128 + 255) / 256, 256, 0, stream>>>(Wg0, W0f, 64, 128);
    k_wprep<<<(128 * 128 + 255) / 256, 256, 0, stream>>>(Wg1, W1f, 128, 128);
    k_wprep<<<(128 * 64 + 255) / 256, 256, 0, stream>>>(Wg2, W2f, 128, 64);

    // MLP (fp32 VALU)
    k_mm<64, 32, 128, true, true, false><<<gN64, 256, 0, stream>>>(x, st, W1, b1, M1, n);
    k_mm<128, 0, 64, true, true, true><<<gN64, 256, 0, stream>>>(M1, nullptr, W2, b2, h0, n);

    // conv0: MFMA mm -> agg@128 (bias+relu, bf16 out)
    k_mmx<64, 128><<<gN64, 256, 0, stream>>>(h0, W0f, P, n);
    k_agg<128, true, true><<<gAgg, 256, 0, stream>>>(P, bg0, dis, offs, ssrc, h1, n);

    // conv1: MFMA mm -> agg@128 (bias+relu, bf16 out)
    k_mmx<128, 128><<<gN64, 256, 0, stream>>>(h1, W1f, P, n);
    k_agg<128, true, true><<<gAgg, 256, 0, stream>>>(P, bg1, dis, offs, ssrc, h2, n);

    // conv2: MFMA mm -> agg@64 (bias, fp32 out) -> d_out
    k_mmx<128, 64><<<gN64, 256, 0, stream>>>(h2, W2f, Q, n);
    k_agg<64, false, false><<<gAgg, 256, 0, stream>>>(Q, bg2, dis, offs, ssrc, (float*)d_out, n);
}